// Round 11
// baseline (1191.846 us; speedup 1.0000x reference)
//
#include <hip/hip_runtime.h>
#include <hip/hip_bf16.h>

// GraphCAD forward on MI355X. All float I/O is f32.
// R17->R18: R17's fused-Pc kernel was structurally right but indexed the
// -qc bias by the DST's graph; the reference uses res[src] = x_s -
// centroid[graph(SRC)]. Edges cross graphs (~15/16), so qc[g_d]-qc[g_s]
// shifted every score ~few e-3 -> absmax 3.6. R18 fixes: biasq[g] = -qc[g],
// epilogue loads ss=src_csr[pos], g_s = ss>>12, adds biasq[g_s] + b1;
// k_fix uses g = s>>12 likewise. Rest identical to R17: MFMA computes
// dx@W1a + xs@W1c in one acc (A = W1a^T,W1c^T RNE-bf16 in 64 VGPR;
// B = DX,XS exact hi+lo splits; 32 MFMA/tile); Pc stream + k_P's Pc half
// eliminated; FIXTH 8e-3 (>=4 sigma of the 1.6e-3 W-RNE score shift)
// defers near-threshold decisions to k_fix's exact f64.

#define D 64
#define BSZ 16
#define NPG 4096
#define NN (BSZ * NPG)   // 65536 nodes
#define NE (NN * 16)     // 1048576 edges
#define NL 2
#define NTILE (NE / 64)  // 16384

#define FIXTH 8e-3f
#define FLAGCAP 65536

// output layout (elements, f32)
#define OUT_X  0u
#define OUT_EW 4194304u
#define OUT_C  5242880u
#define OUT_XL 5243904u
#define OUT_CL 9438208u
#define OUT_PA 9439232u

typedef __attribute__((ext_vector_type(8))) short short8;   // 8 bf16 (4 VGPR)
typedef __attribute__((ext_vector_type(4))) float f32x4;

#define MFMA16(a, b, c) __builtin_amdgcn_mfma_f32_16x16x32_bf16((a), (b), (c), 0, 0, 0)

__device__ __forceinline__ void atomAdd64(double* p, double v) { unsafeAtomicAdd(p, v); }

// ================= CSR build (dst is a static input; rebuilt per call) ======
__global__ __launch_bounds__(256) void k_deg(const int* __restrict__ edst,
                                             int* __restrict__ cnt) {
    int stride = gridDim.x * 256;
    for (int e = blockIdx.x * 256 + threadIdx.x; e < NE; e += stride)
        atomicAdd(&cnt[edst[e]], 1);
}

__global__ __launch_bounds__(256) void k_scan1(const int* __restrict__ cnt,
                                               int* __restrict__ rowptr,
                                               int* __restrict__ bsum) {
    __shared__ int sd[256];
    const int b = blockIdx.x, t = threadIdx.x;
    const int v = cnt[b * 256 + t];
    sd[t] = v;
    __syncthreads();
    for (int off = 1; off < 256; off <<= 1) {
        int tmp = (t >= off) ? sd[t - off] : 0;
        __syncthreads();
        sd[t] += tmp;
        __syncthreads();
    }
    rowptr[b * 256 + t] = sd[t] - v;  // exclusive
    if (t == 255) bsum[b] = sd[255];
}

__global__ __launch_bounds__(256) void k_scan2(int* __restrict__ bsum) {
    __shared__ int sd[256];
    const int t = threadIdx.x;
    const int v = bsum[t];
    sd[t] = v;
    __syncthreads();
    for (int off = 1; off < 256; off <<= 1) {
        int tmp = (t >= off) ? sd[t - off] : 0;
        __syncthreads();
        sd[t] += tmp;
        __syncthreads();
    }
    bsum[t] = sd[t] - v;  // exclusive
}

__global__ __launch_bounds__(256) void k_scan3(const int* __restrict__ bsum,
                                               int* __restrict__ rowptr,
                                               int* __restrict__ cursor) {
    const int i = blockIdx.x * 256 + threadIdx.x;
    const int r = rowptr[i] + bsum[blockIdx.x];
    rowptr[i] = r;
    cursor[i] = r;
    if (i == 0) rowptr[NN] = NE;
}

// fill CSR: slot -> original edge (eord), src (src_csr), dst (dst_csr).
__global__ __launch_bounds__(256) void k_fill(const int* __restrict__ esrc,
                                              const int* __restrict__ edst,
                                              int* __restrict__ cursor,
                                              int* __restrict__ eord,
                                              int* __restrict__ src_csr,
                                              int* __restrict__ dst_csr) {
    int stride = gridDim.x * 256;
    for (int e = blockIdx.x * 256 + threadIdx.x; e < NE; e += stride) {
        const int d = edst[e];
        int pos = atomicAdd(&cursor[d], 1);
        eord[pos] = e;
        src_csr[pos] = esrc[e];
        dst_csr[pos] = d;
    }
}

// ---- initial centroid: per-graph mean of x (f32 in, f64 out), 8 blocks/graph
__global__ __launch_bounds__(256) void k_centroid0(const float* __restrict__ xin,
                                                   double* __restrict__ c64) {
    const int g = blockIdx.x >> 3, sub = blockIdx.x & 7, tid = threadIdx.x;
    const int r = tid >> 6, f = tid & 63;
    __shared__ double cr[4][D];
    double s = 0.0;
    for (int k = 0; k < NPG / 8 / 4; ++k) {
        size_t n = (size_t)g * NPG + (size_t)(sub * (NPG / 8) + 4 * k + r);
        s += (double)xin[n * D + f];
    }
    cr[r][f] = s;
    __syncthreads();
    if (tid < D)
        atomAdd64(&c64[g * D + tid],
                  (cr[0][tid] + cr[1][tid] + cr[2][tid] + cr[3][tid]) * (1.0 / NPG));
}

// ---- qb = c @ W1b, qc = c @ W1c (per graph, f64); biasq = -qc (f32) ----
__global__ __launch_bounds__(256) void k_qbc(const double* __restrict__ c64,
                                             const float* __restrict__ epW1,
                                             double* __restrict__ qb, double* __restrict__ qc,
                                             float* __restrict__ biasq) {
    int gj = blockIdx.x * 256 + threadIdx.x;
    if (gj >= BSZ * D) return;
    int g = gj >> 6, j = gj & 63;
    double sb = 0.0, sc = 0.0;
#pragma unroll
    for (int i = 0; i < D; ++i) {
        double cv = c64[g * D + i];
        sb += cv * (double)epW1[(D + i) * D + j];
        sc += cv * (double)epW1[(2 * D + i) * D + j];
    }
    qb[gj] = sb;
    qc[gj] = sc;
    biasq[gj] = (float)(-sc);
}

// ---- P'_b = x@W1b - qb[g]; f64 compute, f32 store (Pc now fused in k_edge) -
template <int LAYER>
__global__ __launch_bounds__(256) void k_P(const float* __restrict__ xin,
                                           const double* __restrict__ x64,
                                           const float* __restrict__ epW1,
                                           const double* __restrict__ qb,
                                           float* __restrict__ Pb,
                                           double* __restrict__ bnacc) {
    if (blockIdx.x == 0 && threadIdx.x < 128) bnacc[threadIdx.x] = 0.0;
    __shared__ double wb[D * D];
    __shared__ double xrow[4][D];
    int tid = threadIdx.x, w = tid >> 6, j = tid & 63;
    for (int idx = tid; idx < D * D; idx += 256) {
        int i = idx >> 6, c = idx & 63;
        wb[idx] = (double)epW1[(D + i) * D + c];
    }
    __syncthreads();
    for (int grp = blockIdx.x; grp < NN / 4; grp += gridDim.x) {
        size_t n = (size_t)grp * 4 + w;
        xrow[w][j] = (LAYER == 0) ? (double)xin[n * D + j] : x64[n * D + j];
        __syncthreads();
        double pb = 0.0;
#pragma unroll
        for (int i = 0; i < D; ++i) pb += xrow[w][i] * wb[i * D + j];
        const int g = (int)(n >> 12);
        Pb[n * D + j] = (float)(pb - qb[g * D + j]);
        __syncthreads();
    }
}

// ---- edge scorer, CSR order: MFMA computes dx@W1a + xs@W1c in one acc ----
// A = W1a^T,W1c^T (RNE bf16, 64 VGPR); B = DX,XS (exact hi+lo splits, LDS).
// Bias: Pb[dst] + b1 - qc[graph(SRC)]. Near-threshold (|score+g| < 8e-3)
// deferred to k_fix (f64). LDS: 4x ushort[64][72] = 36.9KB (W staged thru 2).
template <int LAYER>
__global__ __launch_bounds__(256) void k_edge(const float* __restrict__ xsrc,
                                              const int* __restrict__ src_csr,
                                              const int* __restrict__ dst_csr,
                                              const int* __restrict__ eord,
                                              const float* __restrict__ ewin,
                                              float* __restrict__ ew_csr,
                                              const float* __restrict__ unoise,
                                              const float* __restrict__ epW1,
                                              const float* __restrict__ epb1,
                                              const float* __restrict__ epW2,
                                              const float* __restrict__ epb2,
                                              const float* __restrict__ alphap,
                                              const float* __restrict__ Pb32,
                                              const float* __restrict__ biasq,
                                              int* __restrict__ flagcnt,
                                              int* __restrict__ flaglist,
                                              float* __restrict__ out) {
    const int t = threadIdx.x;
    const int w = t >> 6, lane = t & 63;
    const int m = lane & 15, hq = lane >> 4;   // col-in-16 / k-group (and row-group)
    const int eloc = t >> 2, q = t & 3;        // staging: slot, quarter

    __shared__ __align__(16) unsigned short DXhi[64][72];  // [slot][k] (init: W1a^T)
    __shared__ __align__(16) unsigned short DXlo[64][72];
    __shared__ __align__(16) unsigned short XShi[64][72];  // [slot][k] (init: W1c^T)
    __shared__ __align__(16) unsigned short XSlo[64][72];

    // ---- W1a^T / W1c^T RNE-bf16 into scratch ----
    for (int idx = t; idx < D * D; idx += 256) {
        const int o = idx >> 6, k = idx & 63;
        unsigned b = __float_as_uint(epW1[k * D + o]);
        DXhi[o][k] = (unsigned short)((b + 0x7FFFu + ((b >> 16) & 1u)) >> 16);
        b = __float_as_uint(epW1[(2 * D + k) * D + o]);
        XShi[o][k] = (unsigned short)((b + 0x7FFFu + ((b >> 16) & 1u)) >> 16);
    }
    const float b2v = epb2[0];
    const float alpha = alphap[0];
    __syncthreads();

    // ---- preload W fragments (tile-invariant): 16 frags = 64 VGPR ----
    short8 wa[4][2], wc[4][2];
#pragma unroll
    for (int ot = 0; ot < 4; ++ot)
#pragma unroll
        for (int c = 0; c < 2; ++c) {
            wa[ot][c] = *(const short8*)&DXhi[16 * ot + m][32 * c + 8 * hq];
            wc[ot][c] = *(const short8*)&XShi[16 * ot + m][32 * c + 8 * hq];
        }
    __syncthreads();  // scratch free -> staging may begin

    for (int tile = blockIdx.x; tile < NTILE; tile += gridDim.x) {
        const int base = tile * 64;

        // ---- stage XS = x_s and DX = |x_d - x_s|, each as bf16 hi+lo ----
        {
            const int pos = base + eloc;
            const int s = src_csr[pos], d = dst_csr[pos];
            const float* rs = xsrc + (size_t)s * D + q * 16;
            const float* rd = xsrc + (size_t)d * D + q * 16;
            unsigned dh[8], dl[8], sh[8], sl[8];
#pragma unroll
            for (int c = 0; c < 4; ++c) {
                const float4 fs = *(const float4*)(rs + 4 * c);
                const float4 fd = *(const float4*)(rd + 4 * c);
                // XS split (truncation hi, residual lo)
                const unsigned sb0 = __float_as_uint(fs.x), sb1 = __float_as_uint(fs.y);
                const unsigned sb2 = __float_as_uint(fs.z), sb3 = __float_as_uint(fs.w);
                const float sl0 = fs.x - __uint_as_float(sb0 & 0xFFFF0000u);
                const float sl1 = fs.y - __uint_as_float(sb1 & 0xFFFF0000u);
                const float sl2 = fs.z - __uint_as_float(sb2 & 0xFFFF0000u);
                const float sl3 = fs.w - __uint_as_float(sb3 & 0xFFFF0000u);
                sh[2 * c + 0] = (sb0 >> 16) | (sb1 & 0xFFFF0000u);
                sh[2 * c + 1] = (sb2 >> 16) | (sb3 & 0xFFFF0000u);
                sl[2 * c + 0] = (__float_as_uint(sl0) >> 16) | (__float_as_uint(sl1) & 0xFFFF0000u);
                sl[2 * c + 1] = (__float_as_uint(sl2) >> 16) | (__float_as_uint(sl3) & 0xFFFF0000u);
                // DX split
                const float d0 = fabsf(fd.x - fs.x), d1 = fabsf(fd.y - fs.y);
                const float d2 = fabsf(fd.z - fs.z), d3 = fabsf(fd.w - fs.w);
                const unsigned b0 = __float_as_uint(d0), b1_ = __float_as_uint(d1);
                const unsigned b2_ = __float_as_uint(d2), b3_ = __float_as_uint(d3);
                const float l0 = d0 - __uint_as_float(b0 & 0xFFFF0000u);
                const float l1 = d1 - __uint_as_float(b1_ & 0xFFFF0000u);
                const float l2 = d2 - __uint_as_float(b2_ & 0xFFFF0000u);
                const float l3 = d3 - __uint_as_float(b3_ & 0xFFFF0000u);
                dh[2 * c + 0] = (b0 >> 16) | (b1_ & 0xFFFF0000u);
                dh[2 * c + 1] = (b2_ >> 16) | (b3_ & 0xFFFF0000u);
                dl[2 * c + 0] = (__float_as_uint(l0) >> 16) | (__float_as_uint(l1) & 0xFFFF0000u);
                dl[2 * c + 1] = (__float_as_uint(l2) >> 16) | (__float_as_uint(l3) & 0xFFFF0000u);
            }
            *(uint4*)&DXhi[eloc][16 * q + 0] = make_uint4(dh[0], dh[1], dh[2], dh[3]);
            *(uint4*)&DXhi[eloc][16 * q + 8] = make_uint4(dh[4], dh[5], dh[6], dh[7]);
            *(uint4*)&DXlo[eloc][16 * q + 0] = make_uint4(dl[0], dl[1], dl[2], dl[3]);
            *(uint4*)&DXlo[eloc][16 * q + 8] = make_uint4(dl[4], dl[5], dl[6], dl[7]);
            *(uint4*)&XShi[eloc][16 * q + 0] = make_uint4(sh[0], sh[1], sh[2], sh[3]);
            *(uint4*)&XShi[eloc][16 * q + 8] = make_uint4(sh[4], sh[5], sh[6], sh[7]);
            *(uint4*)&XSlo[eloc][16 * q + 0] = make_uint4(sl[0], sl[1], sl[2], sl[3]);
            *(uint4*)&XSlo[eloc][16 * q + 8] = make_uint4(sl[4], sl[5], sl[6], sl[7]);
        }
        __syncthreads();

        // ---- MFMA: acc = W1a^T@DX + W1c^T@XS (slots 16w..16w+15) ----
        f32x4 acc[4];
#pragma unroll
        for (int ot = 0; ot < 4; ++ot) {
            f32x4 z = {0.0f, 0.0f, 0.0f, 0.0f};
            acc[ot] = z;
        }
        const int brow = 16 * w + m;
#pragma unroll
        for (int c = 0; c < 2; ++c) {
            const short8 dxh = *(const short8*)&DXhi[brow][32 * c + 8 * hq];
            const short8 dxl = *(const short8*)&DXlo[brow][32 * c + 8 * hq];
            const short8 xsh = *(const short8*)&XShi[brow][32 * c + 8 * hq];
            const short8 xsl = *(const short8*)&XSlo[brow][32 * c + 8 * hq];
#pragma unroll
            for (int ot = 0; ot < 4; ++ot) {
                acc[ot] = MFMA16(wa[ot][c], dxh, acc[ot]);
                acc[ot] = MFMA16(wa[ot][c], dxl, acc[ot]);
                acc[ot] = MFMA16(wc[ot][c], xsh, acc[ot]);
                acc[ot] = MFMA16(wc[ot][c], xsl, acc[ot]);
            }
        }
        __syncthreads();  // B consumed; next tile's staging may overwrite

        // ---- epilogue: slot = 16w + m (lane-fixed); outs = 16ot + 4hq + reg
        // C/D (m89-verified): col = lane&15 = slot-in-wave, row = 4*hq + reg.
        {
            const int pos = base + 16 * w + m;
            const int dd = dst_csr[pos];
            const int ss = src_csr[pos];
            const int gs = ss >> 12;  // graph of the SOURCE node (R17 bugfix)
            const float* pbr = Pb32 + (size_t)dd * D + 4 * hq;
            const float* bqr = biasq + gs * D + 4 * hq;
            float part = 0.0f;
#pragma unroll
            for (int ot = 0; ot < 4; ++ot) {
                const float4 pb = *(const float4*)(pbr + 16 * ot);
                const float4 bq = *(const float4*)(bqr + 16 * ot);
                const float4 b1 = *(const float4*)(epb1 + 16 * ot + 4 * hq);
                const float4 w2 = *(const float4*)(epW2 + 16 * ot + 4 * hq);
                float h;
                h = acc[ot][0] + pb.x + bq.x + b1.x;
                if (h > 0.0f) part += h * w2.x;
                h = acc[ot][1] + pb.y + bq.y + b1.y;
                if (h > 0.0f) part += h * w2.y;
                h = acc[ot][2] + pb.z + bq.z + b1.z;
                if (h > 0.0f) part += h * w2.z;
                h = acc[ot][3] + pb.w + bq.w + b1.w;
                if (h > 0.0f) part += h * w2.w;
            }
            // reduce across the 4 hq-groups sharing this slot
            part += __shfl_xor(part, 16);
            part += __shfl_xor(part, 32);
            if (hq == 0) {  // one sampling lane per slot
                const float sc_ = part + b2v;
                const int e = eord[pos];
                const float u = unoise[(size_t)LAYER * NE + e];
                const float gn = logf(u) - log1pf(-u);
                const float mar = sc_ + gn;  // samp == (mar > 0)
                bool deferred = false;
                if (fabsf(mar) < FIXTH) {
                    int slot = atomicAdd(flagcnt, 1);
                    if (slot < FLAGCAP) {
                        flaglist[slot] = pos;
                        deferred = true;  // k_fix decides + writes this edge
                    }
                }
                if (!deferred) {
                    const float pre = 1.0f / (1.0f + expf(-sc_));
                    const bool samp = mar > 0.0f;
                    const float ewo = (LAYER == 0) ? ewin[e] : ew_csr[pos];
                    const float ewn = samp ? alpha * ewo + (1.0f - alpha) * pre : 0.0f;
                    ew_csr[pos] = ewn;
                    if (LAYER == NL - 1) {
                        out[OUT_EW + (size_t)e] = ewn;
                        out[OUT_PA + (size_t)e] = pre;
                    }
                }
            }
        }
    }
}

// ---- exact f64 re-decision for near-threshold edges (one wave per edge) ----
// Computes the Pc term itself: sum xs*W1c - qc[graph(src)] (f64).
template <int LAYER>
__global__ __launch_bounds__(256) void k_fix(const float* __restrict__ xsrc,
                                             const int* __restrict__ src_csr,
                                             const int* __restrict__ dst_csr,
                                             const int* __restrict__ eord,
                                             const float* __restrict__ ewin,
                                             float* __restrict__ ew_csr,
                                             const float* __restrict__ unoise,
                                             const float* __restrict__ epW1,
                                             const float* __restrict__ epb1,
                                             const float* __restrict__ epW2,
                                             const float* __restrict__ epb2,
                                             const float* __restrict__ alphap,
                                             const float* __restrict__ Pb32,
                                             const double* __restrict__ qc64,
                                             const int* __restrict__ flagcnt,
                                             const int* __restrict__ flaglist,
                                             float* __restrict__ out) {
    const int n = min(flagcnt[0], FLAGCAP);
    __shared__ float dxs[4][D];
    __shared__ float xss[4][D];
    const int w = threadIdx.x >> 6, lane = threadIdx.x & 63;
    const int nw = gridDim.x * 4;
    for (int i = blockIdx.x * 4 + w; i < n; i += nw) {
        const int pos = flaglist[i];
        const int s = src_csr[pos], d = dst_csr[pos];
        const int gs = s >> 12;  // graph of the SOURCE node (R17 bugfix)
        const float xsv = xsrc[(size_t)s * D + lane];
        dxs[w][lane] = fabsf(xsrc[(size_t)d * D + lane] - xsv);
        xss[w][lane] = xsv;
        // wave-internal broadcast (same-wave DS in-order)
        double h = 0.0;
#pragma unroll
        for (int k = 0; k < D; ++k) {
            h += (double)dxs[w][k] * (double)epW1[k * D + lane];
            h += (double)xss[w][k] * (double)epW1[(2 * D + k) * D + lane];
        }
        h += (double)Pb32[(size_t)d * D + lane] - qc64[gs * D + lane] + (double)epb1[lane];
        double part = (h > 0.0) ? h * (double)epW2[lane] : 0.0;
#pragma unroll
        for (int off = 32; off; off >>= 1) part += __shfl_xor(part, off);
        if (lane == 0) {
            const double sc_ = part + (double)epb2[0];
            const int e = eord[pos];
            const double u = (double)unoise[(size_t)LAYER * NE + e];
            const double gn = log(u) - log1p(-u);
            const double pre = 1.0 / (1.0 + exp(-sc_));
            const bool samp = (sc_ + gn) > 0.0;
            const double ewo = (LAYER == 0) ? (double)ewin[e] : (double)ew_csr[pos];
            const double alpha = (double)alphap[0];
            const double ewn = samp ? alpha * ewo + (1.0 - alpha) * pre : 0.0;
            ew_csr[pos] = (float)ewn;
            if (LAYER == NL - 1) {
                out[OUT_EW + (size_t)e] = (float)ewn;
                out[OUT_PA + (size_t)e] = (float)pre;
            }
        }
    }
}

// ---- node update: CSR gather (row-parallel loads) + GIN mlp + BN partials --
template <int LAYER>
__global__ __launch_bounds__(256) void k_nodeup(const float* __restrict__ xsrc,
                                                const float* __restrict__ ew_csr,
                                                const int* __restrict__ src_csr,
                                                const int* __restrict__ rowptr,
                                                const float* __restrict__ ginW,
                                                const float* __restrict__ ginB,
                                                double* __restrict__ xh,
                                                double* __restrict__ bnacc) {
    __shared__ float wg[D * D];
    __shared__ double rowbuf[4][D];
    __shared__ double bn1[4][D];
    __shared__ double bn2[4][D];
    const int t = threadIdx.x, w = t >> 6, lane = t & 63;
    const int e = lane >> 4, q = lane & 15;  // slot, quarter (dims 4q..4q+3)
    for (int idx = t; idx < D * D; idx += 256) wg[idx] = ginW[LAYER * D * D + idx];
    const double bj = (double)ginB[LAYER * D + lane];
    __syncthreads();
    double s1 = 0.0, s2 = 0.0;
    const int nwaves = gridDim.x * 4;
    for (int n = blockIdx.x * 4 + w; n < NN; n += nwaves) {
        const int rs = rowptr[n], re = rowptr[n + 1];
        const int deg = re - rs;
        // ---- first 16 edges: 4 masked slots x 4 chunks, all loads up front
        const int i0 = rs + ((e < deg) ? e : 0);
        const int i1 = rs + ((4 + e < deg) ? 4 + e : 0);
        const int i2 = rs + ((8 + e < deg) ? 8 + e : 0);
        const int i3 = rs + ((12 + e < deg) ? 12 + e : 0);
        const float w0 = (e < deg) ? ew_csr[i0] : 0.f;
        const float w1 = (4 + e < deg) ? ew_csr[i1] : 0.f;
        const float w2 = (8 + e < deg) ? ew_csr[i2] : 0.f;
        const float w3 = (12 + e < deg) ? ew_csr[i3] : 0.f;
        const int s0 = src_csr[i0], s1_ = src_csr[i1];
        const int s2_ = src_csr[i2], s3_ = src_csr[i3];
        const float4 r0 = *(const float4*)(xsrc + (size_t)s0 * D + 4 * q);
        const float4 r1 = *(const float4*)(xsrc + (size_t)s1_ * D + 4 * q);
        const float4 r2 = *(const float4*)(xsrc + (size_t)s2_ * D + 4 * q);
        const float4 r3 = *(const float4*)(xsrc + (size_t)s3_ * D + 4 * q);
        const float4 rf = *(const float4*)(xsrc + (size_t)n * D + 4 * q);  // self
        double a0 = (double)w0 * (double)r0.x;
        double a1 = (double)w0 * (double)r0.y;
        double a2 = (double)w0 * (double)r0.z;
        double a3 = (double)w0 * (double)r0.w;
        a0 += (double)w1 * (double)r1.x;
        a1 += (double)w1 * (double)r1.y;
        a2 += (double)w1 * (double)r1.z;
        a3 += (double)w1 * (double)r1.w;
        a0 += (double)w2 * (double)r2.x;
        a1 += (double)w2 * (double)r2.y;
        a2 += (double)w2 * (double)r2.z;
        a3 += (double)w2 * (double)r2.w;
        a0 += (double)w3 * (double)r3.x;
        a1 += (double)w3 * (double)r3.y;
        a2 += (double)w3 * (double)r3.z;
        a3 += (double)w3 * (double)r3.w;
        // ---- tail: edges beyond 16, masked chunks of 4 (wave-uniform bound)
        for (int k = rs + 16; k < re; k += 4) {
            const int kk = k + e;
            const bool v = kk < re;
            const float wt = v ? ew_csr[kk] : 0.f;
            const int st = src_csr[v ? kk : rs];
            const float4 rt = *(const float4*)(xsrc + (size_t)st * D + 4 * q);
            a0 += (double)wt * (double)rt.x;
            a1 += (double)wt * (double)rt.y;
            a2 += (double)wt * (double)rt.z;
            a3 += (double)wt * (double)rt.w;
        }
        // ---- tree-reduce the 4 slots (lanes differing in bits 4,5) ----
        a0 += __shfl_xor(a0, 16);
        a1 += __shfl_xor(a1, 16);
        a2 += __shfl_xor(a2, 16);
        a3 += __shfl_xor(a3, 16);
        a0 += __shfl_xor(a0, 32);
        a1 += __shfl_xor(a1, 32);
        a2 += __shfl_xor(a2, 32);
        a3 += __shfl_xor(a3, 32);
        // ---- + self, publish to rowbuf (same-wave DS in-order) ----
        if (e == 0) {
            rowbuf[w][4 * q + 0] = a0 + (double)rf.x;
            rowbuf[w][4 * q + 1] = a1 + (double)rf.y;
            rowbuf[w][4 * q + 2] = a2 + (double)rf.z;
            rowbuf[w][4 * q + 3] = a3 + (double)rf.w;
        }
        // ---- GIN matvec (f64) ----
        double h = bj;
#pragma unroll
        for (int i = 0; i < D; ++i) h += rowbuf[w][i] * (double)wg[i * D + lane];
        h = h > 0.0 ? h : 0.0;
        xh[(size_t)n * D + lane] = h;
        s1 += h;
        s2 += h * h;
    }
    // ---- block-level reduce, then 2 atomics per lane-column per block ----
    bn1[w][lane] = s1;
    bn2[w][lane] = s2;
    __syncthreads();
    if (w == 0) {
        atomAdd64(&bnacc[lane], bn1[0][lane] + bn1[1][lane] + bn1[2][lane] + bn1[3][lane]);
        atomAdd64(&bnacc[64 + lane], bn2[0][lane] + bn2[1][lane] + bn2[2][lane] + bn2[3][lane]);
    }
}

// ---- BN finalize ----
__global__ __launch_bounds__(64) void k_bnfin(int layer, const float* __restrict__ gamma,
                                              const float* __restrict__ beta,
                                              const double* __restrict__ bnacc,
                                              double* __restrict__ bnsc) {
    int j = threadIdx.x;
    double mu = bnacc[j] * (1.0 / NN);
    double var = bnacc[64 + j] * (1.0 / NN) - mu * mu;
    double sc = (double)gamma[layer * D + j] / sqrt(var + 1e-5);
    bnsc[j] = sc;
    bnsc[64 + j] = (double)beta[layer * D + j] - mu * sc;
}

// ---- BN apply -> x64 (+x32 mirror for edge/nodeup staging; final out) ----
template <int LAYER>
__global__ __launch_bounds__(256) void k_bnapply(const double* __restrict__ bnsc,
                                                 const double* __restrict__ xh,
                                                 double* __restrict__ x64,
                                                 float* __restrict__ x32,
                                                 float* __restrict__ out) {
    size_t stride = (size_t)gridDim.x * 256;
    for (size_t i = (size_t)blockIdx.x * 256 + threadIdx.x; i < (size_t)NN * D; i += stride) {
        int j = (int)(i & 63);
        double v = bnsc[j] * xh[i] + bnsc[64 + j];
        x64[i] = v;
        if (LAYER == 0) x32[i] = (float)v;
        if (LAYER == NL - 1) out[OUT_X + i] = (float)v;
    }
}

// ---- attention pooling, parallelized: 4 kernels ----
__global__ __launch_bounds__(256) void k_att1(const double* __restrict__ x64,
                                              const double* __restrict__ c64,
                                              double* __restrict__ sc,
                                              double* __restrict__ bmax) {
    const int blk = blockIdx.x, t = threadIdx.x, w = t >> 6, lane = t & 63;
    const int g = blk >> 6;
    __shared__ double wmax[4];
    const double cj = c64[g * D + lane];
    double locmax = -1e300;
    for (int m = 0; m < 16; ++m) {
        const int n = blk * 64 + w * 16 + m;
        double v = x64[(size_t)n * D + lane] * cj;
#pragma unroll
        for (int off = 32; off; off >>= 1) v += __shfl_xor(v, off);
        if (lane == 0) sc[n] = v;
        locmax = fmax(locmax, v);
    }
    if (lane == 0) wmax[w] = locmax;
    __syncthreads();
    if (t == 0) bmax[blk] = fmax(fmax(wmax[0], wmax[1]), fmax(wmax[2], wmax[3]));
}

__global__ __launch_bounds__(64) void k_att2(const double* __restrict__ bmax,
                                             double* __restrict__ mxg,
                                             double* __restrict__ num,
                                             double* __restrict__ den) {
    const int g = blockIdx.x, t = threadIdx.x;
    double m = bmax[g * 64 + t];
#pragma unroll
    for (int off = 32; off; off >>= 1) m = fmax(m, __shfl_xor(m, off));
    if (t == 0) {
        mxg[g] = m;
        den[g] = 0.0;
    }
    num[g * D + t] = 0.0;
}

__global__ __launch_bounds__(256) void k_att3(const double* __restrict__ x64,
                                              const double* __restrict__ sc,
                                              const double* __restrict__ mxg,
                                              double* __restrict__ num,
                                              double* __restrict__ den) {
    const int blk = blockIdx.x, t = threadIdx.x, w = t >> 6, lane = t & 63;
    const int g = blk >> 6;
    __shared__ double cp[4][D];
    __shared__ double wes[4];
    const double mx = mxg[g];
    double accj = 0.0, esum = 0.0;
    for (int m = 0; m < 16; ++m) {
        const int n = blk * 64 + w * 16 + m;
        const double e = exp(sc[n] - mx);
        accj += e * x64[(size_t)n * D + lane];
        esum += e;
    }
    cp[w][lane] = accj;
    if (lane == 0) wes[w] = esum;
    __syncthreads();
    if (t < D) {
        atomAdd64(&num[g * D + t], cp[0][t] + cp[1][t] + cp[2][t] + cp[3][t]);
        if (t == 0) atomAdd64(&den[g], wes[0] + wes[1] + wes[2] + wes[3]);
    }
}

__global__ __launch_bounds__(64) void k_att4(const double* __restrict__ num,
                                             const double* __restrict__ den,
                                             double* __restrict__ c64) {
    const int g = blockIdx.x, t = threadIdx.x;
    c64[g * D + t] = num[g * D + t] / den[g];
}

// ---- head: relu(x@W1+b1)@W2+b2 for all nodes + 16 centroid rows (f32) ----
__global__ __launch_bounds__(256) void k_head(const double* __restrict__ x64,
                                              const double* __restrict__ c64,
                                              const float* __restrict__ hW1,
                                              const float* __restrict__ hb1,
                                              const float* __restrict__ hW2,
                                              const float* __restrict__ hb2,
                                              float* __restrict__ out) {
    __shared__ float w1[D * D];
    __shared__ float w2[D * D];
    __shared__ float xr[4][D];
    __shared__ float hr[4][D];
    int tid = threadIdx.x, w = tid >> 6, j = tid & 63;
    for (int idx = tid; idx < D * D; idx += 256) {
        w1[idx] = hW1[idx];
        w2[idx] = hW2[idx];
    }
    const float b1j = hb1[j];
    const float b2j = hb2[j];
    __syncthreads();
    const int ROWS = NN + BSZ;
    for (int grp = blockIdx.x; grp * 4 < ROWS; grp += gridDim.x) {
        int r = grp * 4 + w;
        bool valid = r < ROWS;
        float xv = 0.f;
        if (valid)
            xv = (r < NN) ? (float)x64[(size_t)r * D + j] : (float)c64[(size_t)(r - NN) * D + j];
        xr[w][j] = xv;
        __syncthreads();
        if (valid) {
            float h = b1j;
#pragma unroll
            for (int i = 0; i < D; ++i) h += xr[w][i] * w1[i * D + j];
            hr[w][j] = h > 0.f ? h : 0.f;
        }
        __syncthreads();
        if (valid) {
            float o = b2j;
#pragma unroll
            for (int i = 0; i < D; ++i) o += hr[w][i] * w2[i * D + j];
            if (r < NN) {
                out[OUT_XL + (size_t)r * D + j] = o;
            } else {
                size_t cr = (size_t)(r - NN) * D + j;
                out[OUT_CL + cr] = o;
                out[OUT_C + cr] = (float)c64[cr];
            }
        }
        __syncthreads();
    }
}

extern "C" void kernel_launch(void* const* d_in, const int* in_sizes, int n_in,
                              void* d_out, int out_size, void* d_ws, size_t ws_size,
                              hipStream_t stream) {
    const float* xin    = (const float*)d_in[0];
    const int*   ei     = (const int*)d_in[1];
    const float* ewin   = (const float*)d_in[2];
    const float* unoise = (const float*)d_in[5];
    const float* epW1   = (const float*)d_in[6];
    const float* epb1   = (const float*)d_in[7];
    const float* epW2   = (const float*)d_in[8];
    const float* epb2   = (const float*)d_in[9];
    const float* alphap = (const float*)d_in[10];
    const float* ginW   = (const float*)d_in[11];
    const float* ginB   = (const float*)d_in[12];
    const float* bng    = (const float*)d_in[13];
    const float* bnb    = (const float*)d_in[14];
    const float* hW1    = (const float*)d_in[15];
    const float* hb1    = (const float*)d_in[16];
    const float* hW2    = (const float*)d_in[17];
    const float* hb2    = (const float*)d_in[18];
    float* out = (float*)d_out;
    const int* esrc = ei;
    const int* edst = ei + NE;

    char* ws = (char*)d_ws;
    const size_t SZ = (size_t)NN * D * sizeof(double);  // 33554432
    double* x64  = (double*)(ws);
    // Pb (k_P->k_edge/k_fix) and xh (k_nodeup->k_bnapply): disjoint live ranges.
    float*  Pb32 = (float*)(ws + SZ);
    double* xh   = (double*)(ws + SZ);
    float*  x32  = (float*)(ws + 2 * SZ);                       // NN*D*4 = 16MB
    float*  ew_csr = (float*)(ws + 2 * SZ + SZ / 2);            // NE*4 (slot is NE*8)
    double* sc   = (double*)(ws + 2 * SZ + SZ / 2 + (size_t)NE * 8);  // NN*8
    char*   p    = ws + 2 * SZ + SZ / 2 + (size_t)NE * 8 + (size_t)NN * 8;
    double* c64  = (double*)p;          p += BSZ * D * 8;
    double* qb   = (double*)p;          p += BSZ * D * 8;
    double* qc   = (double*)p;          p += BSZ * D * 8;
    float*  biasq = (float*)p;          p += BSZ * D * 4;
    double* bnacc = (double*)p;         p += 128 * 8;
    double* bnsc  = (double*)p;         p += 128 * 8;
    double* bmax  = (double*)p;         p += 1024 * 8;
    double* mxg   = (double*)p;         p += 16 * 8;
    double* num   = (double*)p;         p += BSZ * D * 8;
    double* den   = (double*)p;         p += 16 * 8;
    // CSR
    int* cnt     = (int*)p;             p += (size_t)NN * 4;
    int* rowptr  = (int*)p;             p += (size_t)(NN + 1) * 4 + 4;
    int* cursor  = (int*)p;             p += (size_t)NN * 4;
    int* bsum    = (int*)p;             p += 256 * 4;
    int* eord    = (int*)p;             p += (size_t)NE * 4;
    int* src_csr = (int*)p;             p += (size_t)NE * 4;
    int* dst_csr = (int*)p;             p += (size_t)NE * 4;
    // near-threshold fixup list
    int* flagcnt  = (int*)p;            p += 8;
    int* flaglist = (int*)p;            p += (size_t)FLAGCAP * 4;

    // ---- CSR build (dst static) ----
    hipMemsetAsync(cnt, 0, (size_t)NN * 4, stream);
    k_deg<<<1024, 256, 0, stream>>>(edst, cnt);
    k_scan1<<<256, 256, 0, stream>>>(cnt, rowptr, bsum);
    k_scan2<<<1, 256, 0, stream>>>(bsum);
    k_scan3<<<256, 256, 0, stream>>>(bsum, rowptr, cursor);
    k_fill<<<1024, 256, 0, stream>>>(esrc, edst, cursor, eord, src_csr, dst_csr);

    hipMemsetAsync(c64, 0, (size_t)BSZ * D * 8, stream);
    k_centroid0<<<BSZ * 8, 256, 0, stream>>>(xin, c64);

    // ---------------- layer 0 ----------------
    k_qbc<<<4, 256, 0, stream>>>(c64, epW1, qb, qc, biasq);
    k_P<0><<<1024, 256, 0, stream>>>(xin, x64, epW1, qb, Pb32, bnacc);
    hipMemsetAsync(flagcnt, 0, 4, stream);
    k_edge<0><<<2048, 256, 0, stream>>>(xin, src_csr, dst_csr, eord, ewin, ew_csr, unoise,
                                        epW1, epb1, epW2, epb2, alphap, Pb32, biasq,
                                        flagcnt, flaglist, out);
    k_fix<0><<<128, 256, 0, stream>>>(xin, src_csr, dst_csr, eord, ewin, ew_csr, unoise,
                                      epW1, epb1, epW2, epb2, alphap, Pb32, qc,
                                      flagcnt, flaglist, out);
    k_nodeup<0><<<2048, 256, 0, stream>>>(xin, ew_csr, src_csr, rowptr, ginW, ginB,
                                          xh, bnacc);
    k_bnfin<<<1, 64, 0, stream>>>(0, bng, bnb, bnacc, bnsc);
    k_bnapply<0><<<2048, 256, 0, stream>>>(bnsc, xh, x64, x32, out);
    k_att1<<<1024, 256, 0, stream>>>(x64, c64, sc, bmax);
    k_att2<<<16, 64, 0, stream>>>(bmax, mxg, num, den);
    k_att3<<<1024, 256, 0, stream>>>(x64, sc, mxg, num, den);
    k_att4<<<16, 64, 0, stream>>>(num, den, c64);

    // ---------------- layer 1 ----------------
    k_qbc<<<4, 256, 0, stream>>>(c64, epW1, qb, qc, biasq);
    k_P<1><<<1024, 256, 0, stream>>>(xin, x64, epW1, qb, Pb32, bnacc);
    hipMemsetAsync(flagcnt, 0, 4, stream);
    k_edge<1><<<2048, 256, 0, stream>>>(x32, src_csr, dst_csr, eord, ewin, ew_csr, unoise,
                                        epW1, epb1, epW2, epb2, alphap, Pb32, biasq,
                                        flagcnt, flaglist, out);
    k_fix<1><<<128, 256, 0, stream>>>(x32, src_csr, dst_csr, eord, ewin, ew_csr, unoise,
                                      epW1, epb1, epW2, epb2, alphap, Pb32, qc,
                                      flagcnt, flaglist, out);
    k_nodeup<1><<<2048, 256, 0, stream>>>(x32, ew_csr, src_csr, rowptr, ginW, ginB,
                                          xh, bnacc);
    k_bnfin<<<1, 64, 0, stream>>>(1, bng, bnb, bnacc, bnsc);
    k_bnapply<1><<<2048, 256, 0, stream>>>(bnsc, xh, x64, x32, out);
    k_att1<<<1024, 256, 0, stream>>>(x64, c64, sc, bmax);
    k_att2<<<16, 64, 0, stream>>>(bmax, mxg, num, den);
    k_att3<<<1024, 256, 0, stream>>>(x64, sc, mxg, num, den);
    k_att4<<<16, 64, 0, stream>>>(num, den, c64);

    // ---------------- heads + centroid output ----------------
    k_head<<<2048, 256, 0, stream>>>(x64, c64, hW1, hb1, hW2, hb2, out);
}

// Round 12
// 1180.542 us; speedup vs baseline: 1.0096x; 1.0096x over previous
//
#include <hip/hip_runtime.h>
#include <hip/hip_bf16.h>

// GraphCAD forward on MI355X. All float I/O is f32.
// R18->R19: k_edge latency-bound, and the mechanism is now identified: hipcc
// emits s_waitcnt vmcnt(0) before every s_barrier (m97), so (a) R16's reg
// prefetch was drained at the barrier (its null result), (b) the block's 4
// waves are LOCKSTEPPED -> ~2 independent streams/CU for ~600cy random-row
// gathers. Fix: wave-autonomous tiles. Each wave owns a 16-edge tile and its
// own LDS quadrant; stage -> MFMA -> epilogue with ZERO __syncthreads in the
// loop (same-wave DS in-order; compiler inserts lgkmcnt waits - same pattern
// as k_nodeup's rowbuf). Per-wave work is byte-identical to R18 (same loads,
// 32 MFMA/16 slots, same math -> no numeric change); only sync removed, so
// resident waves drift apart and hide each other's latency. W staged once
// through the flat-viewed LDS with 2 barriers before the loop.
// All other kernels identical to R18.

#define D 64
#define BSZ 16
#define NPG 4096
#define NN (BSZ * NPG)   // 65536 nodes
#define NE (NN * 16)     // 1048576 edges
#define NL 2
#define NWT (NE / 16)    // 65536 wave-tiles

#define FIXTH 8e-3f
#define FLAGCAP 65536

// output layout (elements, f32)
#define OUT_X  0u
#define OUT_EW 4194304u
#define OUT_C  5242880u
#define OUT_XL 5243904u
#define OUT_CL 9438208u
#define OUT_PA 9439232u

typedef __attribute__((ext_vector_type(8))) short short8;   // 8 bf16 (4 VGPR)
typedef __attribute__((ext_vector_type(4))) float f32x4;

#define MFMA16(a, b, c) __builtin_amdgcn_mfma_f32_16x16x32_bf16((a), (b), (c), 0, 0, 0)

__device__ __forceinline__ void atomAdd64(double* p, double v) { unsafeAtomicAdd(p, v); }

// ================= CSR build (dst is a static input; rebuilt per call) ======
__global__ __launch_bounds__(256) void k_deg(const int* __restrict__ edst,
                                             int* __restrict__ cnt) {
    int stride = gridDim.x * 256;
    for (int e = blockIdx.x * 256 + threadIdx.x; e < NE; e += stride)
        atomicAdd(&cnt[edst[e]], 1);
}

__global__ __launch_bounds__(256) void k_scan1(const int* __restrict__ cnt,
                                               int* __restrict__ rowptr,
                                               int* __restrict__ bsum) {
    __shared__ int sd[256];
    const int b = blockIdx.x, t = threadIdx.x;
    const int v = cnt[b * 256 + t];
    sd[t] = v;
    __syncthreads();
    for (int off = 1; off < 256; off <<= 1) {
        int tmp = (t >= off) ? sd[t - off] : 0;
        __syncthreads();
        sd[t] += tmp;
        __syncthreads();
    }
    rowptr[b * 256 + t] = sd[t] - v;  // exclusive
    if (t == 255) bsum[b] = sd[255];
}

__global__ __launch_bounds__(256) void k_scan2(int* __restrict__ bsum) {
    __shared__ int sd[256];
    const int t = threadIdx.x;
    const int v = bsum[t];
    sd[t] = v;
    __syncthreads();
    for (int off = 1; off < 256; off <<= 1) {
        int tmp = (t >= off) ? sd[t - off] : 0;
        __syncthreads();
        sd[t] += tmp;
        __syncthreads();
    }
    bsum[t] = sd[t] - v;  // exclusive
}

__global__ __launch_bounds__(256) void k_scan3(const int* __restrict__ bsum,
                                               int* __restrict__ rowptr,
                                               int* __restrict__ cursor) {
    const int i = blockIdx.x * 256 + threadIdx.x;
    const int r = rowptr[i] + bsum[blockIdx.x];
    rowptr[i] = r;
    cursor[i] = r;
    if (i == 0) rowptr[NN] = NE;
}

// fill CSR: slot -> original edge (eord), src (src_csr), dst (dst_csr).
__global__ __launch_bounds__(256) void k_fill(const int* __restrict__ esrc,
                                              const int* __restrict__ edst,
                                              int* __restrict__ cursor,
                                              int* __restrict__ eord,
                                              int* __restrict__ src_csr,
                                              int* __restrict__ dst_csr) {
    int stride = gridDim.x * 256;
    for (int e = blockIdx.x * 256 + threadIdx.x; e < NE; e += stride) {
        const int d = edst[e];
        int pos = atomicAdd(&cursor[d], 1);
        eord[pos] = e;
        src_csr[pos] = esrc[e];
        dst_csr[pos] = d;
    }
}

// ---- initial centroid: per-graph mean of x (f32 in, f64 out), 8 blocks/graph
__global__ __launch_bounds__(256) void k_centroid0(const float* __restrict__ xin,
                                                   double* __restrict__ c64) {
    const int g = blockIdx.x >> 3, sub = blockIdx.x & 7, tid = threadIdx.x;
    const int r = tid >> 6, f = tid & 63;
    __shared__ double cr[4][D];
    double s = 0.0;
    for (int k = 0; k < NPG / 8 / 4; ++k) {
        size_t n = (size_t)g * NPG + (size_t)(sub * (NPG / 8) + 4 * k + r);
        s += (double)xin[n * D + f];
    }
    cr[r][f] = s;
    __syncthreads();
    if (tid < D)
        atomAdd64(&c64[g * D + tid],
                  (cr[0][tid] + cr[1][tid] + cr[2][tid] + cr[3][tid]) * (1.0 / NPG));
}

// ---- qb = c @ W1b, qc = c @ W1c (per graph, f64); biasq = -qc (f32) ----
__global__ __launch_bounds__(256) void k_qbc(const double* __restrict__ c64,
                                             const float* __restrict__ epW1,
                                             double* __restrict__ qb, double* __restrict__ qc,
                                             float* __restrict__ biasq) {
    int gj = blockIdx.x * 256 + threadIdx.x;
    if (gj >= BSZ * D) return;
    int g = gj >> 6, j = gj & 63;
    double sb = 0.0, sc = 0.0;
#pragma unroll
    for (int i = 0; i < D; ++i) {
        double cv = c64[g * D + i];
        sb += cv * (double)epW1[(D + i) * D + j];
        sc += cv * (double)epW1[(2 * D + i) * D + j];
    }
    qb[gj] = sb;
    qc[gj] = sc;
    biasq[gj] = (float)(-sc);
}

// ---- P'_b = x@W1b - qb[g]; f64 compute, f32 store (Pc fused in k_edge) ----
template <int LAYER>
__global__ __launch_bounds__(256) void k_P(const float* __restrict__ xin,
                                           const double* __restrict__ x64,
                                           const float* __restrict__ epW1,
                                           const double* __restrict__ qb,
                                           float* __restrict__ Pb,
                                           double* __restrict__ bnacc) {
    if (blockIdx.x == 0 && threadIdx.x < 128) bnacc[threadIdx.x] = 0.0;
    __shared__ double wb[D * D];
    __shared__ double xrow[4][D];
    int tid = threadIdx.x, w = tid >> 6, j = tid & 63;
    for (int idx = tid; idx < D * D; idx += 256) {
        int i = idx >> 6, c = idx & 63;
        wb[idx] = (double)epW1[(D + i) * D + c];
    }
    __syncthreads();
    for (int grp = blockIdx.x; grp < NN / 4; grp += gridDim.x) {
        size_t n = (size_t)grp * 4 + w;
        xrow[w][j] = (LAYER == 0) ? (double)xin[n * D + j] : x64[n * D + j];
        __syncthreads();
        double pb = 0.0;
#pragma unroll
        for (int i = 0; i < D; ++i) pb += xrow[w][i] * wb[i * D + j];
        const int g = (int)(n >> 12);
        Pb[n * D + j] = (float)(pb - qb[g * D + j]);
        __syncthreads();
    }
}

// ---- edge scorer: WAVE-AUTONOMOUS 16-edge tiles, zero in-loop barriers ----
// Per wave: own LDS quadrant [16][72] x4; stage XS/DX bf16 hi+lo; MFMA
// acc = W1a^T@DX + W1c^T@XS (W frags in 64 VGPR); epilogue + sample.
// Bias: Pb[dst] + b1 - qc[graph(src)]. |score+g| < FIXTH -> k_fix (f64).
template <int LAYER>
__global__ __launch_bounds__(256) void k_edge(const float* __restrict__ xsrc,
                                              const int* __restrict__ src_csr,
                                              const int* __restrict__ dst_csr,
                                              const int* __restrict__ eord,
                                              const float* __restrict__ ewin,
                                              float* __restrict__ ew_csr,
                                              const float* __restrict__ unoise,
                                              const float* __restrict__ epW1,
                                              const float* __restrict__ epb1,
                                              const float* __restrict__ epW2,
                                              const float* __restrict__ epb2,
                                              const float* __restrict__ alphap,
                                              const float* __restrict__ Pb32,
                                              const float* __restrict__ biasq,
                                              int* __restrict__ flagcnt,
                                              int* __restrict__ flaglist,
                                              float* __restrict__ out) {
    const int t = threadIdx.x;
    const int w = t >> 6, lane = t & 63;
    const int m = lane & 15, hq = lane >> 4;   // slot-in-tile / k-group (row-group)
    const int el = lane >> 2, q = lane & 3;    // staging: edge-in-tile, quarter

    __shared__ __align__(16) unsigned short DXhi[4][16][72];
    __shared__ __align__(16) unsigned short DXlo[4][16][72];
    __shared__ __align__(16) unsigned short XShi[4][16][72];
    __shared__ __align__(16) unsigned short XSlo[4][16][72];

    // ---- W1a^T / W1c^T RNE-bf16 staged through the flat-viewed LDS ----
    {
        unsigned short(*Wa)[72] = (unsigned short(*)[72]) & DXhi[0][0][0];  // [64][72]
        unsigned short(*Wc)[72] = (unsigned short(*)[72]) & XShi[0][0][0];
        for (int idx = t; idx < D * D; idx += 256) {
            const int o = idx >> 6, k = idx & 63;
            unsigned b = __float_as_uint(epW1[k * D + o]);
            Wa[o][k] = (unsigned short)((b + 0x7FFFu + ((b >> 16) & 1u)) >> 16);
            b = __float_as_uint(epW1[(2 * D + k) * D + o]);
            Wc[o][k] = (unsigned short)((b + 0x7FFFu + ((b >> 16) & 1u)) >> 16);
        }
        __syncthreads();
        // preload W fragments (tile-invariant): 16 frags = 64 VGPR
    }
    short8 wa[4][2], wc[4][2];
    {
        unsigned short(*Wa)[72] = (unsigned short(*)[72]) & DXhi[0][0][0];
        unsigned short(*Wc)[72] = (unsigned short(*)[72]) & XShi[0][0][0];
#pragma unroll
        for (int ot = 0; ot < 4; ++ot)
#pragma unroll
            for (int c = 0; c < 2; ++c) {
                wa[ot][c] = *(const short8*)&Wa[16 * ot + m][32 * c + 8 * hq];
                wc[ot][c] = *(const short8*)&Wc[16 * ot + m][32 * c + 8 * hq];
            }
        __syncthreads();  // scratch free; NO MORE BARRIERS below
    }
    const float b2v = epb2[0];
    const float alpha = alphap[0];
    const int wid = blockIdx.x * 4 + w;
    const int nwaves = gridDim.x * 4;

    for (int wt = wid; wt < NWT; wt += nwaves) {
        const int base = wt * 16;

        // ---- stage XS = x_s and DX = |x_d - x_s|, bf16 hi+lo (own quadrant)
        {
            const int pos = base + el;
            const int s = src_csr[pos], d = dst_csr[pos];
            const float* rs = xsrc + (size_t)s * D + q * 16;
            const float* rd = xsrc + (size_t)d * D + q * 16;
            unsigned dh[8], dl[8], sh[8], sl[8];
#pragma unroll
            for (int c = 0; c < 4; ++c) {
                const float4 fs = *(const float4*)(rs + 4 * c);
                const float4 fd = *(const float4*)(rd + 4 * c);
                const unsigned sb0 = __float_as_uint(fs.x), sb1 = __float_as_uint(fs.y);
                const unsigned sb2 = __float_as_uint(fs.z), sb3 = __float_as_uint(fs.w);
                const float sl0 = fs.x - __uint_as_float(sb0 & 0xFFFF0000u);
                const float sl1 = fs.y - __uint_as_float(sb1 & 0xFFFF0000u);
                const float sl2 = fs.z - __uint_as_float(sb2 & 0xFFFF0000u);
                const float sl3 = fs.w - __uint_as_float(sb3 & 0xFFFF0000u);
                sh[2 * c + 0] = (sb0 >> 16) | (sb1 & 0xFFFF0000u);
                sh[2 * c + 1] = (sb2 >> 16) | (sb3 & 0xFFFF0000u);
                sl[2 * c + 0] = (__float_as_uint(sl0) >> 16) | (__float_as_uint(sl1) & 0xFFFF0000u);
                sl[2 * c + 1] = (__float_as_uint(sl2) >> 16) | (__float_as_uint(sl3) & 0xFFFF0000u);
                const float d0 = fabsf(fd.x - fs.x), d1 = fabsf(fd.y - fs.y);
                const float d2 = fabsf(fd.z - fs.z), d3 = fabsf(fd.w - fs.w);
                const unsigned b0 = __float_as_uint(d0), b1_ = __float_as_uint(d1);
                const unsigned b2_ = __float_as_uint(d2), b3_ = __float_as_uint(d3);
                const float l0 = d0 - __uint_as_float(b0 & 0xFFFF0000u);
                const float l1 = d1 - __uint_as_float(b1_ & 0xFFFF0000u);
                const float l2 = d2 - __uint_as_float(b2_ & 0xFFFF0000u);
                const float l3 = d3 - __uint_as_float(b3_ & 0xFFFF0000u);
                dh[2 * c + 0] = (b0 >> 16) | (b1_ & 0xFFFF0000u);
                dh[2 * c + 1] = (b2_ >> 16) | (b3_ & 0xFFFF0000u);
                dl[2 * c + 0] = (__float_as_uint(l0) >> 16) | (__float_as_uint(l1) & 0xFFFF0000u);
                dl[2 * c + 1] = (__float_as_uint(l2) >> 16) | (__float_as_uint(l3) & 0xFFFF0000u);
            }
            *(uint4*)&DXhi[w][el][16 * q + 0] = make_uint4(dh[0], dh[1], dh[2], dh[3]);
            *(uint4*)&DXhi[w][el][16 * q + 8] = make_uint4(dh[4], dh[5], dh[6], dh[7]);
            *(uint4*)&DXlo[w][el][16 * q + 0] = make_uint4(dl[0], dl[1], dl[2], dl[3]);
            *(uint4*)&DXlo[w][el][16 * q + 8] = make_uint4(dl[4], dl[5], dl[6], dl[7]);
            *(uint4*)&XShi[w][el][16 * q + 0] = make_uint4(sh[0], sh[1], sh[2], sh[3]);
            *(uint4*)&XShi[w][el][16 * q + 8] = make_uint4(sh[4], sh[5], sh[6], sh[7]);
            *(uint4*)&XSlo[w][el][16 * q + 0] = make_uint4(sl[0], sl[1], sl[2], sl[3]);
            *(uint4*)&XSlo[w][el][16 * q + 8] = make_uint4(sl[4], sl[5], sl[6], sl[7]);
        }
        // same-wave DS in-order: ds_reads below see this wave's writes.

        // ---- MFMA: acc = W1a^T@DX + W1c^T@XS (16 slots of this wave) ----
        f32x4 acc[4];
#pragma unroll
        for (int ot = 0; ot < 4; ++ot) {
            f32x4 z = {0.0f, 0.0f, 0.0f, 0.0f};
            acc[ot] = z;
        }
#pragma unroll
        for (int c = 0; c < 2; ++c) {
            const short8 dxh = *(const short8*)&DXhi[w][m][32 * c + 8 * hq];
            const short8 dxl = *(const short8*)&DXlo[w][m][32 * c + 8 * hq];
            const short8 xsh = *(const short8*)&XShi[w][m][32 * c + 8 * hq];
            const short8 xsl = *(const short8*)&XSlo[w][m][32 * c + 8 * hq];
#pragma unroll
            for (int ot = 0; ot < 4; ++ot) {
                acc[ot] = MFMA16(wa[ot][c], dxh, acc[ot]);
                acc[ot] = MFMA16(wa[ot][c], dxl, acc[ot]);
                acc[ot] = MFMA16(wc[ot][c], xsh, acc[ot]);
                acc[ot] = MFMA16(wc[ot][c], xsl, acc[ot]);
            }
        }

        // ---- epilogue: slot = m (lane-fixed); outs = 16ot + 4hq + reg ----
        // C/D (m89-verified): col = lane&15 = slot, row = 4*hq + reg.
        {
            const int pos = base + m;
            const int dd = dst_csr[pos];
            const int ss = src_csr[pos];
            const int gs = ss >> 12;  // graph of the SOURCE node
            const float* pbr = Pb32 + (size_t)dd * D + 4 * hq;
            const float* bqr = biasq + gs * D + 4 * hq;
            float part = 0.0f;
#pragma unroll
            for (int ot = 0; ot < 4; ++ot) {
                const float4 pb = *(const float4*)(pbr + 16 * ot);
                const float4 bq = *(const float4*)(bqr + 16 * ot);
                const float4 b1 = *(const float4*)(epb1 + 16 * ot + 4 * hq);
                const float4 w2 = *(const float4*)(epW2 + 16 * ot + 4 * hq);
                float h;
                h = acc[ot][0] + pb.x + bq.x + b1.x;
                if (h > 0.0f) part += h * w2.x;
                h = acc[ot][1] + pb.y + bq.y + b1.y;
                if (h > 0.0f) part += h * w2.y;
                h = acc[ot][2] + pb.z + bq.z + b1.z;
                if (h > 0.0f) part += h * w2.z;
                h = acc[ot][3] + pb.w + bq.w + b1.w;
                if (h > 0.0f) part += h * w2.w;
            }
            part += __shfl_xor(part, 16);
            part += __shfl_xor(part, 32);
            if (hq == 0) {  // one sampling lane per slot
                const float sc_ = part + b2v;
                const int e = eord[pos];
                const float u = unoise[(size_t)LAYER * NE + e];
                const float gn = logf(u) - log1pf(-u);
                const float mar = sc_ + gn;  // samp == (mar > 0)
                bool deferred = false;
                if (fabsf(mar) < FIXTH) {
                    int slot = atomicAdd(flagcnt, 1);
                    if (slot < FLAGCAP) {
                        flaglist[slot] = pos;
                        deferred = true;  // k_fix decides + writes this edge
                    }
                }
                if (!deferred) {
                    const float pre = 1.0f / (1.0f + expf(-sc_));
                    const bool samp = mar > 0.0f;
                    const float ewo = (LAYER == 0) ? ewin[e] : ew_csr[pos];
                    const float ewn = samp ? alpha * ewo + (1.0f - alpha) * pre : 0.0f;
                    ew_csr[pos] = ewn;
                    if (LAYER == NL - 1) {
                        out[OUT_EW + (size_t)e] = ewn;
                        out[OUT_PA + (size_t)e] = pre;
                    }
                }
            }
        }
    }
}

// ---- exact f64 re-decision for near-threshold edges (one wave per edge) ----
// Computes the Pc term itself: sum xs*W1c - qc[graph(src)] (f64).
template <int LAYER>
__global__ __launch_bounds__(256) void k_fix(const float* __restrict__ xsrc,
                                             const int* __restrict__ src_csr,
                                             const int* __restrict__ dst_csr,
                                             const int* __restrict__ eord,
                                             const float* __restrict__ ewin,
                                             float* __restrict__ ew_csr,
                                             const float* __restrict__ unoise,
                                             const float* __restrict__ epW1,
                                             const float* __restrict__ epb1,
                                             const float* __restrict__ epW2,
                                             const float* __restrict__ epb2,
                                             const float* __restrict__ alphap,
                                             const float* __restrict__ Pb32,
                                             const double* __restrict__ qc64,
                                             const int* __restrict__ flagcnt,
                                             const int* __restrict__ flaglist,
                                             float* __restrict__ out) {
    const int n = min(flagcnt[0], FLAGCAP);
    __shared__ float dxs[4][D];
    __shared__ float xss[4][D];
    const int w = threadIdx.x >> 6, lane = threadIdx.x & 63;
    const int nw = gridDim.x * 4;
    for (int i = blockIdx.x * 4 + w; i < n; i += nw) {
        const int pos = flaglist[i];
        const int s = src_csr[pos], d = dst_csr[pos];
        const int gs = s >> 12;  // graph of the SOURCE node
        const float xsv = xsrc[(size_t)s * D + lane];
        dxs[w][lane] = fabsf(xsrc[(size_t)d * D + lane] - xsv);
        xss[w][lane] = xsv;
        // wave-internal broadcast (same-wave DS in-order)
        double h = 0.0;
#pragma unroll
        for (int k = 0; k < D; ++k) {
            h += (double)dxs[w][k] * (double)epW1[k * D + lane];
            h += (double)xss[w][k] * (double)epW1[(2 * D + k) * D + lane];
        }
        h += (double)Pb32[(size_t)d * D + lane] - qc64[gs * D + lane] + (double)epb1[lane];
        double part = (h > 0.0) ? h * (double)epW2[lane] : 0.0;
#pragma unroll
        for (int off = 32; off; off >>= 1) part += __shfl_xor(part, off);
        if (lane == 0) {
            const double sc_ = part + (double)epb2[0];
            const int e = eord[pos];
            const double u = (double)unoise[(size_t)LAYER * NE + e];
            const double gn = log(u) - log1p(-u);
            const double pre = 1.0 / (1.0 + exp(-sc_));
            const bool samp = (sc_ + gn) > 0.0;
            const double ewo = (LAYER == 0) ? (double)ewin[e] : (double)ew_csr[pos];
            const double alpha = (double)alphap[0];
            const double ewn = samp ? alpha * ewo + (1.0 - alpha) * pre : 0.0;
            ew_csr[pos] = (float)ewn;
            if (LAYER == NL - 1) {
                out[OUT_EW + (size_t)e] = (float)ewn;
                out[OUT_PA + (size_t)e] = (float)pre;
            }
        }
    }
}

// ---- node update: CSR gather (row-parallel loads) + GIN mlp + BN partials --
template <int LAYER>
__global__ __launch_bounds__(256) void k_nodeup(const float* __restrict__ xsrc,
                                                const float* __restrict__ ew_csr,
                                                const int* __restrict__ src_csr,
                                                const int* __restrict__ rowptr,
                                                const float* __restrict__ ginW,
                                                const float* __restrict__ ginB,
                                                double* __restrict__ xh,
                                                double* __restrict__ bnacc) {
    __shared__ float wg[D * D];
    __shared__ double rowbuf[4][D];
    __shared__ double bn1[4][D];
    __shared__ double bn2[4][D];
    const int t = threadIdx.x, w = t >> 6, lane = t & 63;
    const int e = lane >> 4, q = lane & 15;  // slot, quarter (dims 4q..4q+3)
    for (int idx = t; idx < D * D; idx += 256) wg[idx] = ginW[LAYER * D * D + idx];
    const double bj = (double)ginB[LAYER * D + lane];
    __syncthreads();
    double s1 = 0.0, s2 = 0.0;
    const int nwaves = gridDim.x * 4;
    for (int n = blockIdx.x * 4 + w; n < NN; n += nwaves) {
        const int rs = rowptr[n], re = rowptr[n + 1];
        const int deg = re - rs;
        // ---- first 16 edges: 4 masked slots x 4 chunks, all loads up front
        const int i0 = rs + ((e < deg) ? e : 0);
        const int i1 = rs + ((4 + e < deg) ? 4 + e : 0);
        const int i2 = rs + ((8 + e < deg) ? 8 + e : 0);
        const int i3 = rs + ((12 + e < deg) ? 12 + e : 0);
        const float w0 = (e < deg) ? ew_csr[i0] : 0.f;
        const float w1 = (4 + e < deg) ? ew_csr[i1] : 0.f;
        const float w2 = (8 + e < deg) ? ew_csr[i2] : 0.f;
        const float w3 = (12 + e < deg) ? ew_csr[i3] : 0.f;
        const int s0 = src_csr[i0], s1_ = src_csr[i1];
        const int s2_ = src_csr[i2], s3_ = src_csr[i3];
        const float4 r0 = *(const float4*)(xsrc + (size_t)s0 * D + 4 * q);
        const float4 r1 = *(const float4*)(xsrc + (size_t)s1_ * D + 4 * q);
        const float4 r2 = *(const float4*)(xsrc + (size_t)s2_ * D + 4 * q);
        const float4 r3 = *(const float4*)(xsrc + (size_t)s3_ * D + 4 * q);
        const float4 rf = *(const float4*)(xsrc + (size_t)n * D + 4 * q);  // self
        double a0 = (double)w0 * (double)r0.x;
        double a1 = (double)w0 * (double)r0.y;
        double a2 = (double)w0 * (double)r0.z;
        double a3 = (double)w0 * (double)r0.w;
        a0 += (double)w1 * (double)r1.x;
        a1 += (double)w1 * (double)r1.y;
        a2 += (double)w1 * (double)r1.z;
        a3 += (double)w1 * (double)r1.w;
        a0 += (double)w2 * (double)r2.x;
        a1 += (double)w2 * (double)r2.y;
        a2 += (double)w2 * (double)r2.z;
        a3 += (double)w2 * (double)r2.w;
        a0 += (double)w3 * (double)r3.x;
        a1 += (double)w3 * (double)r3.y;
        a2 += (double)w3 * (double)r3.z;
        a3 += (double)w3 * (double)r3.w;
        // ---- tail: edges beyond 16, masked chunks of 4 (wave-uniform bound)
        for (int k = rs + 16; k < re; k += 4) {
            const int kk = k + e;
            const bool v = kk < re;
            const float wt = v ? ew_csr[kk] : 0.f;
            const int st = src_csr[v ? kk : rs];
            const float4 rt = *(const float4*)(xsrc + (size_t)st * D + 4 * q);
            a0 += (double)wt * (double)rt.x;
            a1 += (double)wt * (double)rt.y;
            a2 += (double)wt * (double)rt.z;
            a3 += (double)wt * (double)rt.w;
        }
        // ---- tree-reduce the 4 slots (lanes differing in bits 4,5) ----
        a0 += __shfl_xor(a0, 16);
        a1 += __shfl_xor(a1, 16);
        a2 += __shfl_xor(a2, 16);
        a3 += __shfl_xor(a3, 16);
        a0 += __shfl_xor(a0, 32);
        a1 += __shfl_xor(a1, 32);
        a2 += __shfl_xor(a2, 32);
        a3 += __shfl_xor(a3, 32);
        // ---- + self, publish to rowbuf (same-wave DS in-order) ----
        if (e == 0) {
            rowbuf[w][4 * q + 0] = a0 + (double)rf.x;
            rowbuf[w][4 * q + 1] = a1 + (double)rf.y;
            rowbuf[w][4 * q + 2] = a2 + (double)rf.z;
            rowbuf[w][4 * q + 3] = a3 + (double)rf.w;
        }
        // ---- GIN matvec (f64) ----
        double h = bj;
#pragma unroll
        for (int i = 0; i < D; ++i) h += rowbuf[w][i] * (double)wg[i * D + lane];
        h = h > 0.0 ? h : 0.0;
        xh[(size_t)n * D + lane] = h;
        s1 += h;
        s2 += h * h;
    }
    // ---- block-level reduce, then 2 atomics per lane-column per block ----
    bn1[w][lane] = s1;
    bn2[w][lane] = s2;
    __syncthreads();
    if (w == 0) {
        atomAdd64(&bnacc[lane], bn1[0][lane] + bn1[1][lane] + bn1[2][lane] + bn1[3][lane]);
        atomAdd64(&bnacc[64 + lane], bn2[0][lane] + bn2[1][lane] + bn2[2][lane] + bn2[3][lane]);
    }
}

// ---- BN finalize ----
__global__ __launch_bounds__(64) void k_bnfin(int layer, const float* __restrict__ gamma,
                                              const float* __restrict__ beta,
                                              const double* __restrict__ bnacc,
                                              double* __restrict__ bnsc) {
    int j = threadIdx.x;
    double mu = bnacc[j] * (1.0 / NN);
    double var = bnacc[64 + j] * (1.0 / NN) - mu * mu;
    double sc = (double)gamma[layer * D + j] / sqrt(var + 1e-5);
    bnsc[j] = sc;
    bnsc[64 + j] = (double)beta[layer * D + j] - mu * sc;
}

// ---- BN apply -> x64 (+x32 mirror for edge/nodeup staging; final out) ----
template <int LAYER>
__global__ __launch_bounds__(256) void k_bnapply(const double* __restrict__ bnsc,
                                                 const double* __restrict__ xh,
                                                 double* __restrict__ x64,
                                                 float* __restrict__ x32,
                                                 float* __restrict__ out) {
    size_t stride = (size_t)gridDim.x * 256;
    for (size_t i = (size_t)blockIdx.x * 256 + threadIdx.x; i < (size_t)NN * D; i += stride) {
        int j = (int)(i & 63);
        double v = bnsc[j] * xh[i] + bnsc[64 + j];
        x64[i] = v;
        if (LAYER == 0) x32[i] = (float)v;
        if (LAYER == NL - 1) out[OUT_X + i] = (float)v;
    }
}

// ---- attention pooling, parallelized: 4 kernels ----
__global__ __launch_bounds__(256) void k_att1(const double* __restrict__ x64,
                                              const double* __restrict__ c64,
                                              double* __restrict__ sc,
                                              double* __restrict__ bmax) {
    const int blk = blockIdx.x, t = threadIdx.x, w = t >> 6, lane = t & 63;
    const int g = blk >> 6;
    __shared__ double wmax[4];
    const double cj = c64[g * D + lane];
    double locmax = -1e300;
    for (int m = 0; m < 16; ++m) {
        const int n = blk * 64 + w * 16 + m;
        double v = x64[(size_t)n * D + lane] * cj;
#pragma unroll
        for (int off = 32; off; off >>= 1) v += __shfl_xor(v, off);
        if (lane == 0) sc[n] = v;
        locmax = fmax(locmax, v);
    }
    if (lane == 0) wmax[w] = locmax;
    __syncthreads();
    if (t == 0) bmax[blk] = fmax(fmax(wmax[0], wmax[1]), fmax(wmax[2], wmax[3]));
}

__global__ __launch_bounds__(64) void k_att2(const double* __restrict__ bmax,
                                             double* __restrict__ mxg,
                                             double* __restrict__ num,
                                             double* __restrict__ den) {
    const int g = blockIdx.x, t = threadIdx.x;
    double m = bmax[g * 64 + t];
#pragma unroll
    for (int off = 32; off; off >>= 1) m = fmax(m, __shfl_xor(m, off));
    if (t == 0) {
        mxg[g] = m;
        den[g] = 0.0;
    }
    num[g * D + t] = 0.0;
}

__global__ __launch_bounds__(256) void k_att3(const double* __restrict__ x64,
                                              const double* __restrict__ sc,
                                              const double* __restrict__ mxg,
                                              double* __restrict__ num,
                                              double* __restrict__ den) {
    const int blk = blockIdx.x, t = threadIdx.x, w = t >> 6, lane = t & 63;
    const int g = blk >> 6;
    __shared__ double cp[4][D];
    __shared__ double wes[4];
    const double mx = mxg[g];
    double accj = 0.0, esum = 0.0;
    for (int m = 0; m < 16; ++m) {
        const int n = blk * 64 + w * 16 + m;
        const double e = exp(sc[n] - mx);
        accj += e * x64[(size_t)n * D + lane];
        esum += e;
    }
    cp[w][lane] = accj;
    if (lane == 0) wes[w] = esum;
    __syncthreads();
    if (t < D) {
        atomAdd64(&num[g * D + t], cp[0][t] + cp[1][t] + cp[2][t] + cp[3][t]);
        if (t == 0) atomAdd64(&den[g], wes[0] + wes[1] + wes[2] + wes[3]);
    }
}

__global__ __launch_bounds__(64) void k_att4(const double* __restrict__ num,
                                             const double* __restrict__ den,
                                             double* __restrict__ c64) {
    const int g = blockIdx.x, t = threadIdx.x;
    c64[g * D + t] = num[g * D + t] / den[g];
}

// ---- head: relu(x@W1+b1)@W2+b2 for all nodes + 16 centroid rows (f32) ----
__global__ __launch_bounds__(256) void k_head(const double* __restrict__ x64,
                                              const double* __restrict__ c64,
                                              const float* __restrict__ hW1,
                                              const float* __restrict__ hb1,
                                              const float* __restrict__ hW2,
                                              const float* __restrict__ hb2,
                                              float* __restrict__ out) {
    __shared__ float w1[D * D];
    __shared__ float w2[D * D];
    __shared__ float xr[4][D];
    __shared__ float hr[4][D];
    int tid = threadIdx.x, w = tid >> 6, j = tid & 63;
    for (int idx = tid; idx < D * D; idx += 256) {
        w1[idx] = hW1[idx];
        w2[idx] = hW2[idx];
    }
    const float b1j = hb1[j];
    const float b2j = hb2[j];
    __syncthreads();
    const int ROWS = NN + BSZ;
    for (int grp = blockIdx.x; grp * 4 < ROWS; grp += gridDim.x) {
        int r = grp * 4 + w;
        bool valid = r < ROWS;
        float xv = 0.f;
        if (valid)
            xv = (r < NN) ? (float)x64[(size_t)r * D + j] : (float)c64[(size_t)(r - NN) * D + j];
        xr[w][j] = xv;
        __syncthreads();
        if (valid) {
            float h = b1j;
#pragma unroll
            for (int i = 0; i < D; ++i) h += xr[w][i] * w1[i * D + j];
            hr[w][j] = h > 0.f ? h : 0.f;
        }
        __syncthreads();
        if (valid) {
            float o = b2j;
#pragma unroll
            for (int i = 0; i < D; ++i) o += hr[w][i] * w2[i * D + j];
            if (r < NN) {
                out[OUT_XL + (size_t)r * D + j] = o;
            } else {
                size_t cr = (size_t)(r - NN) * D + j;
                out[OUT_CL + cr] = o;
                out[OUT_C + cr] = (float)c64[cr];
            }
        }
        __syncthreads();
    }
}

extern "C" void kernel_launch(void* const* d_in, const int* in_sizes, int n_in,
                              void* d_out, int out_size, void* d_ws, size_t ws_size,
                              hipStream_t stream) {
    const float* xin    = (const float*)d_in[0];
    const int*   ei     = (const int*)d_in[1];
    const float* ewin   = (const float*)d_in[2];
    const float* unoise = (const float*)d_in[5];
    const float* epW1   = (const float*)d_in[6];
    const float* epb1   = (const float*)d_in[7];
    const float* epW2   = (const float*)d_in[8];
    const float* epb2   = (const float*)d_in[9];
    const float* alphap = (const float*)d_in[10];
    const float* ginW   = (const float*)d_in[11];
    const float* ginB   = (const float*)d_in[12];
    const float* bng    = (const float*)d_in[13];
    const float* bnb    = (const float*)d_in[14];
    const float* hW1    = (const float*)d_in[15];
    const float* hb1    = (const float*)d_in[16];
    const float* hW2    = (const float*)d_in[17];
    const float* hb2    = (const float*)d_in[18];
    float* out = (float*)d_out;
    const int* esrc = ei;
    const int* edst = ei + NE;

    char* ws = (char*)d_ws;
    const size_t SZ = (size_t)NN * D * sizeof(double);  // 33554432
    double* x64  = (double*)(ws);
    // Pb (k_P->k_edge/k_fix) and xh (k_nodeup->k_bnapply): disjoint live ranges.
    float*  Pb32 = (float*)(ws + SZ);
    double* xh   = (double*)(ws + SZ);
    float*  x32  = (float*)(ws + 2 * SZ);                       // NN*D*4 = 16MB
    float*  ew_csr = (float*)(ws + 2 * SZ + SZ / 2);            // NE*4 (slot is NE*8)
    double* sc   = (double*)(ws + 2 * SZ + SZ / 2 + (size_t)NE * 8);  // NN*8
    char*   p    = ws + 2 * SZ + SZ / 2 + (size_t)NE * 8 + (size_t)NN * 8;
    double* c64  = (double*)p;          p += BSZ * D * 8;
    double* qb   = (double*)p;          p += BSZ * D * 8;
    double* qc   = (double*)p;          p += BSZ * D * 8;
    float*  biasq = (float*)p;          p += BSZ * D * 4;
    double* bnacc = (double*)p;         p += 128 * 8;
    double* bnsc  = (double*)p;         p += 128 * 8;
    double* bmax  = (double*)p;         p += 1024 * 8;
    double* mxg   = (double*)p;         p += 16 * 8;
    double* num   = (double*)p;         p += BSZ * D * 8;
    double* den   = (double*)p;         p += 16 * 8;
    // CSR
    int* cnt     = (int*)p;             p += (size_t)NN * 4;
    int* rowptr  = (int*)p;             p += (size_t)(NN + 1) * 4 + 4;
    int* cursor  = (int*)p;             p += (size_t)NN * 4;
    int* bsum    = (int*)p;             p += 256 * 4;
    int* eord    = (int*)p;             p += (size_t)NE * 4;
    int* src_csr = (int*)p;             p += (size_t)NE * 4;
    int* dst_csr = (int*)p;             p += (size_t)NE * 4;
    // near-threshold fixup list
    int* flagcnt  = (int*)p;            p += 8;
    int* flaglist = (int*)p;            p += (size_t)FLAGCAP * 4;

    // ---- CSR build (dst static) ----
    hipMemsetAsync(cnt, 0, (size_t)NN * 4, stream);
    k_deg<<<1024, 256, 0, stream>>>(edst, cnt);
    k_scan1<<<256, 256, 0, stream>>>(cnt, rowptr, bsum);
    k_scan2<<<1, 256, 0, stream>>>(bsum);
    k_scan3<<<256, 256, 0, stream>>>(bsum, rowptr, cursor);
    k_fill<<<1024, 256, 0, stream>>>(esrc, edst, cursor, eord, src_csr, dst_csr);

    hipMemsetAsync(c64, 0, (size_t)BSZ * D * 8, stream);
    k_centroid0<<<BSZ * 8, 256, 0, stream>>>(xin, c64);

    // ---------------- layer 0 ----------------
    k_qbc<<<4, 256, 0, stream>>>(c64, epW1, qb, qc, biasq);
    k_P<0><<<1024, 256, 0, stream>>>(xin, x64, epW1, qb, Pb32, bnacc);
    hipMemsetAsync(flagcnt, 0, 4, stream);
    k_edge<0><<<2048, 256, 0, stream>>>(xin, src_csr, dst_csr, eord, ewin, ew_csr, unoise,
                                        epW1, epb1, epW2, epb2, alphap, Pb32, biasq,
                                        flagcnt, flaglist, out);
    k_fix<0><<<128, 256, 0, stream>>>(xin, src_csr, dst_csr, eord, ewin, ew_csr, unoise,
                                      epW1, epb1, epW2, epb2, alphap, Pb32, qc,
                                      flagcnt, flaglist, out);
    k_nodeup<0><<<2048, 256, 0, stream>>>(xin, ew_csr, src_csr, rowptr, ginW, ginB,
                                          xh, bnacc);
    k_bnfin<<<1, 64, 0, stream>>>(0, bng, bnb, bnacc, bnsc);
    k_bnapply<0><<<2048, 256, 0, stream>>>(bnsc, xh, x64, x32, out);
    k_att1<<<1024, 256, 0, stream>>>(x64, c64, sc, bmax);
    k_att2<<<16, 64, 0, stream>>>(bmax, mxg, num, den);
    k_att3<<<1024, 256, 0, stream>>>(x64, sc, mxg, num, den);
    k_att4<<<16, 64, 0, stream>>>(num, den, c64);

    // ---------------- layer 1 ----------------
    k_qbc<<<4, 256, 0, stream>>>(c64, epW1, qb, qc, biasq);
    k_P<1><<<1024, 256, 0, stream>>>(xin, x64, epW1, qb, Pb32, bnacc);
    hipMemsetAsync(flagcnt, 0, 4, stream);
    k_edge<1><<<2048, 256, 0, stream>>>(x32, src_csr, dst_csr, eord, ewin, ew_csr, unoise,
                                        epW1, epb1, epW2, epb2, alphap, Pb32, biasq,
                                        flagcnt, flaglist, out);
    k_fix<1><<<128, 256, 0, stream>>>(x32, src_csr, dst_csr, eord, ewin, ew_csr, unoise,
                                      epW1, epb1, epW2, epb2, alphap, Pb32, qc,
                                      flagcnt, flaglist, out);
    k_nodeup<1><<<2048, 256, 0, stream>>>(x32, ew_csr, src_csr, rowptr, ginW, ginB,
                                          xh, bnacc);
    k_bnfin<<<1, 64, 0, stream>>>(1, bng, bnb, bnacc, bnsc);
    k_bnapply<1><<<2048, 256, 0, stream>>>(bnsc, xh, x64, x32, out);
    k_att1<<<1024, 256, 0, stream>>>(x64, c64, sc, bmax);
    k_att2<<<16, 64, 0, stream>>>(bmax, mxg, num, den);
    k_att3<<<1024, 256, 0, stream>>>(x64, sc, mxg, num, den);
    k_att4<<<16, 64, 0, stream>>>(num, den, c64);

    // ---------------- heads + centroid output ----------------
    k_head<<<2048, 256, 0, stream>>>(x64, c64, hW1, hb1, hW2, hb2, out);
}

// Round 13
// 964.468 us; speedup vs baseline: 1.2358x; 1.2240x over previous
//
#include <hip/hip_runtime.h>
#include <hip/hip_bf16.h>

// GraphCAD forward on MI355X. All float I/O is f32.
// R19->R20: six rounds of k_edge surgery (MFMA, byte cuts, barrier removal)
// all land at 208-222us vs R13's 177us: k_edge is latency/occupancy-bound
// and R13's 52-VGPR f32-GEMM shape (occ 39%, below the VGPR=64 wave-halving
// cliff, m69) is the local optimum. R20 reverts k_edge/k_fix/k_nodeup to
// R13 verbatim and instead strips f64 from the REST of the pipeline:
// (1) k_P computes Pb/Pc in f32 (stored f32 anyway; ~1e-6 shift, read
// consistently by both k_edge and k_fix under the FIXTH=2e-3 guard);
// (2) x64 deleted: bnapply computes BN affine in f64, writes x32 once;
// k_nodeup stores xh as f32 (BN stats still from unrounded f64 h);
// att1/att3/head read x32 (math f64). Halves bnapply/att/head traffic.
// xh32 aliases Pb32 (disjoint live ranges).

#define D 64
#define BSZ 16
#define NPG 4096
#define NN (BSZ * NPG)   // 65536 nodes
#define NE (NN * 16)     // 1048576 edges
#define NL 2
#define NTILE (NE / 64)  // 16384

#define FIXTH 2e-3f
#define FLAGCAP 65536

// output layout (elements, f32)
#define OUT_X  0u
#define OUT_EW 4194304u
#define OUT_C  5242880u
#define OUT_XL 5243904u
#define OUT_CL 9438208u
#define OUT_PA 9439232u

__device__ __forceinline__ void atomAdd64(double* p, double v) { unsafeAtomicAdd(p, v); }

// ================= CSR build (dst is a static input; rebuilt per call) ======
__global__ __launch_bounds__(256) void k_deg(const int* __restrict__ edst,
                                             int* __restrict__ cnt) {
    int stride = gridDim.x * 256;
    for (int e = blockIdx.x * 256 + threadIdx.x; e < NE; e += stride)
        atomicAdd(&cnt[edst[e]], 1);
}

__global__ __launch_bounds__(256) void k_scan1(const int* __restrict__ cnt,
                                               int* __restrict__ rowptr,
                                               int* __restrict__ bsum) {
    __shared__ int sd[256];
    const int b = blockIdx.x, t = threadIdx.x;
    const int v = cnt[b * 256 + t];
    sd[t] = v;
    __syncthreads();
    for (int off = 1; off < 256; off <<= 1) {
        int tmp = (t >= off) ? sd[t - off] : 0;
        __syncthreads();
        sd[t] += tmp;
        __syncthreads();
    }
    rowptr[b * 256 + t] = sd[t] - v;  // exclusive
    if (t == 255) bsum[b] = sd[255];
}

__global__ __launch_bounds__(256) void k_scan2(int* __restrict__ bsum) {
    __shared__ int sd[256];
    const int t = threadIdx.x;
    const int v = bsum[t];
    sd[t] = v;
    __syncthreads();
    for (int off = 1; off < 256; off <<= 1) {
        int tmp = (t >= off) ? sd[t - off] : 0;
        __syncthreads();
        sd[t] += tmp;
        __syncthreads();
    }
    bsum[t] = sd[t] - v;  // exclusive
}

__global__ __launch_bounds__(256) void k_scan3(const int* __restrict__ bsum,
                                               int* __restrict__ rowptr,
                                               int* __restrict__ cursor) {
    const int i = blockIdx.x * 256 + threadIdx.x;
    const int r = rowptr[i] + bsum[blockIdx.x];
    rowptr[i] = r;
    cursor[i] = r;
    if (i == 0) rowptr[NN] = NE;
}

// fill CSR: slot -> original edge (eord), src (src_csr), dst (dst_csr).
__global__ __launch_bounds__(256) void k_fill(const int* __restrict__ esrc,
                                              const int* __restrict__ edst,
                                              int* __restrict__ cursor,
                                              int* __restrict__ eord,
                                              int* __restrict__ src_csr,
                                              int* __restrict__ dst_csr) {
    int stride = gridDim.x * 256;
    for (int e = blockIdx.x * 256 + threadIdx.x; e < NE; e += stride) {
        const int d = edst[e];
        int pos = atomicAdd(&cursor[d], 1);
        eord[pos] = e;
        src_csr[pos] = esrc[e];
        dst_csr[pos] = d;
    }
}

// ---- initial centroid: per-graph mean of x (f32 in, f64 out), 8 blocks/graph
__global__ __launch_bounds__(256) void k_centroid0(const float* __restrict__ xin,
                                                   double* __restrict__ c64) {
    const int g = blockIdx.x >> 3, sub = blockIdx.x & 7, tid = threadIdx.x;
    const int r = tid >> 6, f = tid & 63;
    __shared__ double cr[4][D];
    double s = 0.0;
    for (int k = 0; k < NPG / 8 / 4; ++k) {
        size_t n = (size_t)g * NPG + (size_t)(sub * (NPG / 8) + 4 * k + r);
        s += (double)xin[n * D + f];
    }
    cr[r][f] = s;
    __syncthreads();
    if (tid < D)
        atomAdd64(&c64[g * D + tid],
                  (cr[0][tid] + cr[1][tid] + cr[2][tid] + cr[3][tid]) * (1.0 / NPG));
}

// ---- qb = c @ W1b, qc = c @ W1c (per graph, f64) ----
__global__ __launch_bounds__(256) void k_qbc(const double* __restrict__ c64,
                                             const float* __restrict__ epW1,
                                             double* __restrict__ qb, double* __restrict__ qc) {
    int gj = blockIdx.x * 256 + threadIdx.x;
    if (gj >= BSZ * D) return;
    int g = gj >> 6, j = gj & 63;
    double sb = 0.0, sc = 0.0;
#pragma unroll
    for (int i = 0; i < D; ++i) {
        double cv = c64[g * D + i];
        sb += cv * (double)epW1[(D + i) * D + j];
        sc += cv * (double)epW1[(2 * D + i) * D + j];
    }
    qb[gj] = sb;
    qc[gj] = sc;
}

// ---- P'_b = x@W1b - qb[g], P'_c = x@W1c - qc[g]; f32 compute/store ----
// f32 shift ~1e-6 on Pb/Pc; k_edge and k_fix both read these same values,
// so decisions stay consistent; |margin|<FIXTH edges go to k_fix regardless.
template <int LAYER>
__global__ __launch_bounds__(256) void k_P(const float* __restrict__ xin,
                                           const float* __restrict__ x32,
                                           const float* __restrict__ epW1,
                                           const double* __restrict__ qb,
                                           const double* __restrict__ qc,
                                           float* __restrict__ Pb, float* __restrict__ Pc,
                                           double* __restrict__ bnacc) {
    if (blockIdx.x == 0 && threadIdx.x < 128) bnacc[threadIdx.x] = 0.0;
    __shared__ float wb[D * D];
    __shared__ float wc[D * D];
    __shared__ float xrow[4][D];
    int tid = threadIdx.x, w = tid >> 6, j = tid & 63;
    for (int idx = tid; idx < D * D; idx += 256) {
        int i = idx >> 6, c = idx & 63;
        wb[idx] = epW1[(D + i) * D + c];
        wc[idx] = epW1[(2 * D + i) * D + c];
    }
    __syncthreads();
    for (int grp = blockIdx.x; grp < NN / 4; grp += gridDim.x) {
        size_t n = (size_t)grp * 4 + w;
        xrow[w][j] = (LAYER == 0) ? xin[n * D + j] : x32[n * D + j];
        __syncthreads();
        float pb = 0.0f, pc = 0.0f;
#pragma unroll
        for (int i = 0; i < D; ++i) {
            const float xv = xrow[w][i];
            pb += xv * wb[i * D + j];
            pc += xv * wc[i * D + j];
        }
        const int g = (int)(n >> 12);
        Pb[n * D + j] = pb - (float)qb[g * D + j];
        Pc[n * D + j] = pc - (float)qc[g * D + j];
        __syncthreads();
    }
}

// ---- edge scorer, CSR order: all-f32 tile GEMM + sample; near-threshold
// ---- edges (|score+g| < FIXTH) deferred to k_fix for exact f64 decision.
// LDS: A f32 [64][68] 17KB (reused as f32 sred), W f32 [64][68] 17KB.
template <int LAYER>
__global__ __launch_bounds__(256, 4) void k_edge(const float* __restrict__ xsrc,
                                                 const int* __restrict__ src_csr,
                                                 const int* __restrict__ dst_csr,
                                                 const int* __restrict__ eord,
                                                 const float* __restrict__ ewin,
                                                 float* __restrict__ ew_csr,
                                                 const float* __restrict__ unoise,
                                                 const float* __restrict__ epW1,
                                                 const float* __restrict__ epb1,
                                                 const float* __restrict__ epW2,
                                                 const float* __restrict__ epb2,
                                                 const float* __restrict__ alphap,
                                                 const float* __restrict__ Pb32,
                                                 const float* __restrict__ Pc32,
                                                 int* __restrict__ flagcnt,
                                                 int* __restrict__ flaglist,
                                                 float* __restrict__ out) {
    const int t = threadIdx.x;
    const int tx = t & 15, ty = t >> 4;

    __shared__ __align__(16) float ldsA[64 * 68];  // |dx| [dim][slot]
    __shared__ float ldsW[64 * 68];                // W1a [k][j]

    for (int idx = t; idx < D * D; idx += 256) {
        int k = idx >> 6, j = idx & 63;
        ldsW[k * 68 + j] = epW1[idx];
    }
    float b1f[4], w2f[4];
#pragma unroll
    for (int c = 0; c < 4; ++c) {
        b1f[c] = epb1[4 * tx + c];
        w2f[c] = epW2[4 * tx + c];
    }
    const float b2v = epb2[0];
    const float alpha = alphap[0];
    __syncthreads();

    const int eloc = t >> 2, q = t & 3;

    for (int tile = blockIdx.x; tile < NTILE; tile += gridDim.x) {
        const int base = tile * 64;

        // ---- stage |x_d - x_s| (f32, transposed). d-rows run-repeat (L1). --
        {
            const int pos = base + eloc;
            const int s = src_csr[pos], d = dst_csr[pos];
            const float* rs = xsrc + (size_t)s * D + q * 16;
            const float* rd = xsrc + (size_t)d * D + q * 16;
#pragma unroll
            for (int c = 0; c < 4; ++c) {
                const float4 fd = *(const float4*)(rd + 4 * c);
                const float4 fs = *(const float4*)(rs + 4 * c);
                const int dim = q * 16 + 4 * c;
                ldsA[(dim + 0) * 68 + eloc] = fabsf(fd.x - fs.x);
                ldsA[(dim + 1) * 68 + eloc] = fabsf(fd.y - fs.y);
                ldsA[(dim + 2) * 68 + eloc] = fabsf(fd.z - fs.z);
                ldsA[(dim + 3) * 68 + eloc] = fabsf(fd.w - fs.w);
            }
        }
        __syncthreads();

        // ---- 64x64x64 GEMM: f32 inputs, f32 accumulate, 4x4 per thread ----
        float acc[4][4];
#pragma unroll
        for (int r = 0; r < 4; ++r)
#pragma unroll
            for (int c = 0; c < 4; ++c) acc[r][c] = 0.0f;

#pragma unroll 4
        for (int k = 0; k < 64; ++k) {
            const float4 af = *(const float4*)&ldsA[k * 68 + 4 * ty];
            const float4 wf = *(const float4*)&ldsW[k * 68 + 4 * tx];
            const float av[4] = {af.x, af.y, af.z, af.w};
            const float wv[4] = {wf.x, wf.y, wf.z, wf.w};
#pragma unroll
            for (int r = 0; r < 4; ++r)
#pragma unroll
                for (int c = 0; c < 4; ++c) acc[r][c] += av[r] * wv[c];
        }
        __syncthreads();  // A dead -> reuse as f32 sred

        float* sred = ldsA;
        // ---- epilogue: + P' terms, +b1, relu, * w2, partial sums ----
#pragma unroll
        for (int r = 0; r < 4; ++r) {
            const int pos = base + 4 * ty + r;
            const int s = src_csr[pos], d = dst_csr[pos];
            const float4 pb = *(const float4*)(Pb32 + (size_t)d * D + 4 * tx);
            const float4 pc = *(const float4*)(Pc32 + (size_t)s * D + 4 * tx);
            float part = 0.0f;
            float h;
            h = acc[r][0] + pb.x + pc.x + b1f[0];
            if (h > 0.0f) part += h * w2f[0];
            h = acc[r][1] + pb.y + pc.y + b1f[1];
            if (h > 0.0f) part += h * w2f[1];
            h = acc[r][2] + pb.z + pc.z + b1f[2];
            if (h > 0.0f) part += h * w2f[2];
            h = acc[r][3] + pb.w + pc.w + b1f[3];
            if (h > 0.0f) part += h * w2f[3];
            sred[(4 * ty + r) * 17 + tx] = part;
        }
        __syncthreads();

        // ---- score reduce + RelaxedBernoulli sample (one lane per slot) ----
        if (t < 64) {
            float sc_ = b2v;
#pragma unroll
            for (int i = 0; i < 16; ++i) sc_ += sred[t * 17 + i];
            const int pos = base + t;
            const int e = eord[pos];
            const float u = unoise[(size_t)LAYER * NE + e];
            const float gn = logf(u) - log1pf(-u);
            const float mar = sc_ + gn;  // decision margin; samp == (mar > 0)
            bool deferred = false;
            if (fabsf(mar) < FIXTH) {
                int slot = atomicAdd(flagcnt, 1);
                if (slot < FLAGCAP) {
                    flaglist[slot] = pos;
                    deferred = true;  // k_fix decides + writes this edge
                }
            }
            if (!deferred) {
                const float pre = 1.0f / (1.0f + expf(-sc_));
                const bool samp = mar > 0.0f;
                const float ewo = (LAYER == 0) ? ewin[e] : ew_csr[pos];
                const float ewn = samp ? alpha * ewo + (1.0f - alpha) * pre : 0.0f;
                ew_csr[pos] = ewn;
                if (LAYER == NL - 1) {
                    out[OUT_EW + (size_t)e] = ewn;
                    out[OUT_PA + (size_t)e] = pre;
                }
            }
        }
        __syncthreads();
    }
}

// ---- exact f64 re-decision for near-threshold edges (one wave per edge) ----
template <int LAYER>
__global__ __launch_bounds__(256) void k_fix(const float* __restrict__ xsrc,
                                             const int* __restrict__ src_csr,
                                             const int* __restrict__ dst_csr,
                                             const int* __restrict__ eord,
                                             const float* __restrict__ ewin,
                                             float* __restrict__ ew_csr,
                                             const float* __restrict__ unoise,
                                             const float* __restrict__ epW1,
                                             const float* __restrict__ epb1,
                                             const float* __restrict__ epW2,
                                             const float* __restrict__ epb2,
                                             const float* __restrict__ alphap,
                                             const float* __restrict__ Pb32,
                                             const float* __restrict__ Pc32,
                                             const int* __restrict__ flagcnt,
                                             const int* __restrict__ flaglist,
                                             float* __restrict__ out) {
    const int n = min(flagcnt[0], FLAGCAP);
    __shared__ float dxs[4][D];
    const int w = threadIdx.x >> 6, lane = threadIdx.x & 63;
    const int nw = gridDim.x * 4;
    for (int i = blockIdx.x * 4 + w; i < n; i += nw) {
        const int pos = flaglist[i];
        const int s = src_csr[pos], d = dst_csr[pos];
        // |dx| from the same f32 inputs the main kernel staged
        dxs[w][lane] = fabsf(xsrc[(size_t)d * D + lane] - xsrc[(size_t)s * D + lane]);
        // wave-internal broadcast (same-wave DS in-order)
        double h = 0.0;
#pragma unroll
        for (int k = 0; k < D; ++k) h += (double)dxs[w][k] * (double)epW1[k * D + lane];
        h += (double)Pb32[(size_t)d * D + lane] + (double)Pc32[(size_t)s * D + lane] +
             (double)epb1[lane];
        double part = (h > 0.0) ? h * (double)epW2[lane] : 0.0;
#pragma unroll
        for (int off = 32; off; off >>= 1) part += __shfl_xor(part, off);
        if (lane == 0) {
            const double sc_ = part + (double)epb2[0];
            const int e = eord[pos];
            const double u = (double)unoise[(size_t)LAYER * NE + e];
            const double gn = log(u) - log1p(-u);
            const double pre = 1.0 / (1.0 + exp(-sc_));
            const bool samp = (sc_ + gn) > 0.0;
            const double ewo = (LAYER == 0) ? (double)ewin[e] : (double)ew_csr[pos];
            const double alpha = (double)alphap[0];
            const double ewn = samp ? alpha * ewo + (1.0 - alpha) * pre : 0.0;
            ew_csr[pos] = (float)ewn;
            if (LAYER == NL - 1) {
                out[OUT_EW + (size_t)e] = (float)ewn;
                out[OUT_PA + (size_t)e] = (float)pre;
            }
        }
    }
}

// ---- node update: CSR gather (row-parallel loads) + GIN mlp + BN partials --
// Lane = (slot e=0..3, quarter q=0..15). First 16 edges: 4 float4-load
// instructions x 4 rows each, issued back-to-back. f64 acc per (slot,4dims);
// tree-reduce slots (2x shfl_xor); + self; f64 matvec; xh stored f32
// (BN stats still from unrounded f64 h). bnacc block-reduced in LDS first.
template <int LAYER>
__global__ __launch_bounds__(256) void k_nodeup(const float* __restrict__ xsrc,
                                                const float* __restrict__ ew_csr,
                                                const int* __restrict__ src_csr,
                                                const int* __restrict__ rowptr,
                                                const float* __restrict__ ginW,
                                                const float* __restrict__ ginB,
                                                float* __restrict__ xh,
                                                double* __restrict__ bnacc) {
    __shared__ float wg[D * D];
    __shared__ double rowbuf[4][D];
    __shared__ double bn1[4][D];
    __shared__ double bn2[4][D];
    const int t = threadIdx.x, w = t >> 6, lane = t & 63;
    const int e = lane >> 4, q = lane & 15;  // slot, quarter (dims 4q..4q+3)
    for (int idx = t; idx < D * D; idx += 256) wg[idx] = ginW[LAYER * D * D + idx];
    const double bj = (double)ginB[LAYER * D + lane];
    __syncthreads();
    double s1 = 0.0, s2 = 0.0;
    const int nwaves = gridDim.x * 4;
    for (int n = blockIdx.x * 4 + w; n < NN; n += nwaves) {
        const int rs = rowptr[n], re = rowptr[n + 1];
        const int deg = re - rs;
        // ---- first 16 edges: 4 masked slots x 4 chunks, all loads up front
        const int i0 = rs + ((e < deg) ? e : 0);
        const int i1 = rs + ((4 + e < deg) ? 4 + e : 0);
        const int i2 = rs + ((8 + e < deg) ? 8 + e : 0);
        const int i3 = rs + ((12 + e < deg) ? 12 + e : 0);
        const float w0 = (e < deg) ? ew_csr[i0] : 0.f;
        const float w1 = (4 + e < deg) ? ew_csr[i1] : 0.f;
        const float w2 = (8 + e < deg) ? ew_csr[i2] : 0.f;
        const float w3 = (12 + e < deg) ? ew_csr[i3] : 0.f;
        const int s0 = src_csr[i0], s1_ = src_csr[i1];
        const int s2_ = src_csr[i2], s3_ = src_csr[i3];
        const float4 r0 = *(const float4*)(xsrc + (size_t)s0 * D + 4 * q);
        const float4 r1 = *(const float4*)(xsrc + (size_t)s1_ * D + 4 * q);
        const float4 r2 = *(const float4*)(xsrc + (size_t)s2_ * D + 4 * q);
        const float4 r3 = *(const float4*)(xsrc + (size_t)s3_ * D + 4 * q);
        const float4 rf = *(const float4*)(xsrc + (size_t)n * D + 4 * q);  // self
        double a0 = (double)w0 * (double)r0.x;
        double a1 = (double)w0 * (double)r0.y;
        double a2 = (double)w0 * (double)r0.z;
        double a3 = (double)w0 * (double)r0.w;
        a0 += (double)w1 * (double)r1.x;
        a1 += (double)w1 * (double)r1.y;
        a2 += (double)w1 * (double)r1.z;
        a3 += (double)w1 * (double)r1.w;
        a0 += (double)w2 * (double)r2.x;
        a1 += (double)w2 * (double)r2.y;
        a2 += (double)w2 * (double)r2.z;
        a3 += (double)w2 * (double)r2.w;
        a0 += (double)w3 * (double)r3.x;
        a1 += (double)w3 * (double)r3.y;
        a2 += (double)w3 * (double)r3.z;
        a3 += (double)w3 * (double)r3.w;
        // ---- tail: edges beyond 16, masked chunks of 4 (wave-uniform bound)
        for (int k = rs + 16; k < re; k += 4) {
            const int kk = k + e;
            const bool v = kk < re;
            const float wt = v ? ew_csr[kk] : 0.f;
            const int st = src_csr[v ? kk : rs];
            const float4 rt = *(const float4*)(xsrc + (size_t)st * D + 4 * q);
            a0 += (double)wt * (double)rt.x;
            a1 += (double)wt * (double)rt.y;
            a2 += (double)wt * (double)rt.z;
            a3 += (double)wt * (double)rt.w;
        }
        // ---- tree-reduce the 4 slots (lanes differing in bits 4,5) ----
        a0 += __shfl_xor(a0, 16);
        a1 += __shfl_xor(a1, 16);
        a2 += __shfl_xor(a2, 16);
        a3 += __shfl_xor(a3, 16);
        a0 += __shfl_xor(a0, 32);
        a1 += __shfl_xor(a1, 32);
        a2 += __shfl_xor(a2, 32);
        a3 += __shfl_xor(a3, 32);
        // ---- + self, publish to rowbuf (same-wave DS in-order) ----
        if (e == 0) {
            rowbuf[w][4 * q + 0] = a0 + (double)rf.x;
            rowbuf[w][4 * q + 1] = a1 + (double)rf.y;
            rowbuf[w][4 * q + 2] = a2 + (double)rf.z;
            rowbuf[w][4 * q + 3] = a3 + (double)rf.w;
        }
        // ---- GIN matvec (f64) ----
        double h = bj;
#pragma unroll
        for (int i = 0; i < D; ++i) h += rowbuf[w][i] * (double)wg[i * D + lane];
        h = h > 0.0 ? h : 0.0;
        xh[(size_t)n * D + lane] = (float)h;
        s1 += h;
        s2 += h * h;
    }
    // ---- block-level reduce, then 2 atomics per lane-column per block ----
    bn1[w][lane] = s1;
    bn2[w][lane] = s2;
    __syncthreads();
    if (w == 0) {
        atomAdd64(&bnacc[lane], bn1[0][lane] + bn1[1][lane] + bn1[2][lane] + bn1[3][lane]);
        atomAdd64(&bnacc[64 + lane], bn2[0][lane] + bn2[1][lane] + bn2[2][lane] + bn2[3][lane]);
    }
}

// ---- BN finalize ----
__global__ __launch_bounds__(64) void k_bnfin(int layer, const float* __restrict__ gamma,
                                              const float* __restrict__ beta,
                                              const double* __restrict__ bnacc,
                                              double* __restrict__ bnsc) {
    int j = threadIdx.x;
    double mu = bnacc[j] * (1.0 / NN);
    double var = bnacc[64 + j] * (1.0 / NN) - mu * mu;
    double sc = (double)gamma[layer * D + j] / sqrt(var + 1e-5);
    bnsc[j] = sc;
    bnsc[64 + j] = (double)beta[layer * D + j] - mu * sc;
}

// ---- BN apply -> x32 (f64 affine, single rounding; final out at layer 1) --
template <int LAYER>
__global__ __launch_bounds__(256) void k_bnapply(const double* __restrict__ bnsc,
                                                 const float* __restrict__ xh,
                                                 float* __restrict__ x32,
                                                 float* __restrict__ out) {
    size_t stride = (size_t)gridDim.x * 256;
    for (size_t i = (size_t)blockIdx.x * 256 + threadIdx.x; i < (size_t)NN * D; i += stride) {
        int j = (int)(i & 63);
        const float v = (float)(bnsc[j] * (double)xh[i] + bnsc[64 + j]);
        x32[i] = v;
        if (LAYER == NL - 1) out[OUT_X + i] = v;
    }
}

// ---- attention pooling, parallelized: 4 kernels (x in f32, math f64) ----
__global__ __launch_bounds__(256) void k_att1(const float* __restrict__ x32,
                                              const double* __restrict__ c64,
                                              double* __restrict__ sc,
                                              double* __restrict__ bmax) {
    const int blk = blockIdx.x, t = threadIdx.x, w = t >> 6, lane = t & 63;
    const int g = blk >> 6;
    __shared__ double wmax[4];
    const double cj = c64[g * D + lane];
    double locmax = -1e300;
    for (int m = 0; m < 16; ++m) {
        const int n = blk * 64 + w * 16 + m;
        double v = (double)x32[(size_t)n * D + lane] * cj;
#pragma unroll
        for (int off = 32; off; off >>= 1) v += __shfl_xor(v, off);
        if (lane == 0) sc[n] = v;
        locmax = fmax(locmax, v);
    }
    if (lane == 0) wmax[w] = locmax;
    __syncthreads();
    if (t == 0) bmax[blk] = fmax(fmax(wmax[0], wmax[1]), fmax(wmax[2], wmax[3]));
}

__global__ __launch_bounds__(64) void k_att2(const double* __restrict__ bmax,
                                             double* __restrict__ mxg,
                                             double* __restrict__ num,
                                             double* __restrict__ den) {
    const int g = blockIdx.x, t = threadIdx.x;
    double m = bmax[g * 64 + t];
#pragma unroll
    for (int off = 32; off; off >>= 1) m = fmax(m, __shfl_xor(m, off));
    if (t == 0) {
        mxg[g] = m;
        den[g] = 0.0;
    }
    num[g * D + t] = 0.0;
}

__global__ __launch_bounds__(256) void k_att3(const float* __restrict__ x32,
                                              const double* __restrict__ sc,
                                              const double* __restrict__ mxg,
                                              double* __restrict__ num,
                                              double* __restrict__ den) {
    const int blk = blockIdx.x, t = threadIdx.x, w = t >> 6, lane = t & 63;
    const int g = blk >> 6;
    __shared__ double cp[4][D];
    __shared__ double wes[4];
    const double mx = mxg[g];
    double accj = 0.0, esum = 0.0;
    for (int m = 0; m < 16; ++m) {
        const int n = blk * 64 + w * 16 + m;
        const double e = exp(sc[n] - mx);
        accj += e * (double)x32[(size_t)n * D + lane];
        esum += e;
    }
    cp[w][lane] = accj;
    if (lane == 0) wes[w] = esum;
    __syncthreads();
    if (t < D) {
        atomAdd64(&num[g * D + t], cp[0][t] + cp[1][t] + cp[2][t] + cp[3][t]);
        if (t == 0) atomAdd64(&den[g], wes[0] + wes[1] + wes[2] + wes[3]);
    }
}

__global__ __launch_bounds__(64) void k_att4(const double* __restrict__ num,
                                             const double* __restrict__ den,
                                             double* __restrict__ c64) {
    const int g = blockIdx.x, t = threadIdx.x;
    c64[g * D + t] = num[g * D + t] / den[g];
}

// ---- head: relu(x@W1+b1)@W2+b2 for all nodes + 16 centroid rows (f32) ----
__global__ __launch_bounds__(256) void k_head(const float* __restrict__ x32,
                                              const double* __restrict__ c64,
                                              const float* __restrict__ hW1,
                                              const float* __restrict__ hb1,
                                              const float* __restrict__ hW2,
                                              const float* __restrict__ hb2,
                                              float* __restrict__ out) {
    __shared__ float w1[D * D];
    __shared__ float w2[D * D];
    __shared__ float xr[4][D];
    __shared__ float hr[4][D];
    int tid = threadIdx.x, w = tid >> 6, j = tid & 63;
    for (int idx = tid; idx < D * D; idx += 256) {
        w1[idx] = hW1[idx];
        w2[idx] = hW2[idx];
    }
    const float b1j = hb1[j];
    const float b2j = hb2[j];
    __syncthreads();
    const int ROWS = NN + BSZ;
    for (int grp = blockIdx.x; grp * 4 < ROWS; grp += gridDim.x) {
        int r = grp * 4 + w;
        bool valid = r < ROWS;
        float xv = 0.f;
        if (valid)
            xv = (r < NN) ? x32[(size_t)r * D + j] : (float)c64[(size_t)(r - NN) * D + j];
        xr[w][j] = xv;
        __syncthreads();
        if (valid) {
            float h = b1j;
#pragma unroll
            for (int i = 0; i < D; ++i) h += xr[w][i] * w1[i * D + j];
            hr[w][j] = h > 0.f ? h : 0.f;
        }
        __syncthreads();
        if (valid) {
            float o = b2j;
#pragma unroll
            for (int i = 0; i < D; ++i) o += hr[w][i] * w2[i * D + j];
            if (r < NN) {
                out[OUT_XL + (size_t)r * D + j] = o;
            } else {
                size_t cr = (size_t)(r - NN) * D + j;
                out[OUT_CL + cr] = o;
                out[OUT_C + cr] = (float)c64[cr];
            }
        }
        __syncthreads();
    }
}

extern "C" void kernel_launch(void* const* d_in, const int* in_sizes, int n_in,
                              void* d_out, int out_size, void* d_ws, size_t ws_size,
                              hipStream_t stream) {
    const float* xin    = (const float*)d_in[0];
    const int*   ei     = (const int*)d_in[1];
    const float* ewin   = (const float*)d_in[2];
    const float* unoise = (const float*)d_in[5];
    const float* epW1   = (const float*)d_in[6];
    const float* epb1   = (const float*)d_in[7];
    const float* epW2   = (const float*)d_in[8];
    const float* epb2   = (const float*)d_in[9];
    const float* alphap = (const float*)d_in[10];
    const float* ginW   = (const float*)d_in[11];
    const float* ginB   = (const float*)d_in[12];
    const float* bng    = (const float*)d_in[13];
    const float* bnb    = (const float*)d_in[14];
    const float* hW1    = (const float*)d_in[15];
    const float* hb1    = (const float*)d_in[16];
    const float* hW2    = (const float*)d_in[17];
    const float* hb2    = (const float*)d_in[18];
    float* out = (float*)d_out;
    const int* esrc = ei;
    const int* edst = ei + NE;

    char* ws = (char*)d_ws;
    const size_t SZ4 = (size_t)NN * D * sizeof(float);  // 16MB
    // Pb (k_P->k_edge/k_fix) and xh (k_nodeup->k_bnapply): disjoint live ranges.
    float* Pb32 = (float*)(ws);
    float* xh32 = Pb32;  // alias
    float* Pc32 = (float*)(ws + SZ4);
    float* x32  = (float*)(ws + 2 * SZ4);
    float* ew_csr = (float*)(ws + 3 * SZ4);                       // NE*4 = 4MB
    double* sc  = (double*)(ws + 3 * SZ4 + (size_t)NE * 4);       // NN*8
    char*  p    = ws + 3 * SZ4 + (size_t)NE * 4 + (size_t)NN * 8;
    double* c64  = (double*)p;          p += BSZ * D * 8;
    double* qb   = (double*)p;          p += BSZ * D * 8;
    double* qc   = (double*)p;          p += BSZ * D * 8;
    double* bnacc = (double*)p;         p += 128 * 8;
    double* bnsc  = (double*)p;         p += 128 * 8;
    double* bmax  = (double*)p;         p += 1024 * 8;
    double* mxg   = (double*)p;         p += 16 * 8;
    double* num   = (double*)p;         p += BSZ * D * 8;
    double* den   = (double*)p;         p += 16 * 8;
    // CSR
    int* cnt     = (int*)p;             p += (size_t)NN * 4;
    int* rowptr  = (int*)p;             p += (size_t)(NN + 1) * 4 + 4;
    int* cursor  = (int*)p;             p += (size_t)NN * 4;
    int* bsum    = (int*)p;             p += 256 * 4;
    int* eord    = (int*)p;             p += (size_t)NE * 4;
    int* src_csr = (int*)p;             p += (size_t)NE * 4;
    int* dst_csr = (int*)p;             p += (size_t)NE * 4;
    // near-threshold fixup list
    int* flagcnt  = (int*)p;            p += 8;
    int* flaglist = (int*)p;            p += (size_t)FLAGCAP * 4;

    // ---- CSR build (dst static) ----
    hipMemsetAsync(cnt, 0, (size_t)NN * 4, stream);
    k_deg<<<1024, 256, 0, stream>>>(edst, cnt);
    k_scan1<<<256, 256, 0, stream>>>(cnt, rowptr, bsum);
    k_scan2<<<1, 256, 0, stream>>>(bsum);
    k_scan3<<<256, 256, 0, stream>>>(bsum, rowptr, cursor);
    k_fill<<<1024, 256, 0, stream>>>(esrc, edst, cursor, eord, src_csr, dst_csr);

    hipMemsetAsync(c64, 0, (size_t)BSZ * D * 8, stream);
    k_centroid0<<<BSZ * 8, 256, 0, stream>>>(xin, c64);

    // ---------------- layer 0 ----------------
    k_qbc<<<4, 256, 0, stream>>>(c64, epW1, qb, qc);
    k_P<0><<<2048, 256, 0, stream>>>(xin, x32, epW1, qb, qc, Pb32, Pc32, bnacc);
    hipMemsetAsync(flagcnt, 0, 4, stream);
    k_edge<0><<<2048, 256, 0, stream>>>(xin, src_csr, dst_csr, eord, ewin, ew_csr, unoise,
                                        epW1, epb1, epW2, epb2, alphap, Pb32, Pc32,
                                        flagcnt, flaglist, out);
    k_fix<0><<<64, 256, 0, stream>>>(xin, src_csr, dst_csr, eord, ewin, ew_csr, unoise,
                                     epW1, epb1, epW2, epb2, alphap, Pb32, Pc32,
                                     flagcnt, flaglist, out);
    k_nodeup<0><<<2048, 256, 0, stream>>>(xin, ew_csr, src_csr, rowptr, ginW, ginB,
                                          xh32, bnacc);
    k_bnfin<<<1, 64, 0, stream>>>(0, bng, bnb, bnacc, bnsc);
    k_bnapply<0><<<2048, 256, 0, stream>>>(bnsc, xh32, x32, out);
    k_att1<<<1024, 256, 0, stream>>>(x32, c64, sc, bmax);
    k_att2<<<16, 64, 0, stream>>>(bmax, mxg, num, den);
    k_att3<<<1024, 256, 0, stream>>>(x32, sc, mxg, num, den);
    k_att4<<<16, 64, 0, stream>>>(num, den, c64);

    // ---------------- layer 1 ----------------
    k_qbc<<<4, 256, 0, stream>>>(c64, epW1, qb, qc);
    k_P<1><<<2048, 256, 0, stream>>>(xin, x32, epW1, qb, qc, Pb32, Pc32, bnacc);
    hipMemsetAsync(flagcnt, 0, 4, stream);
    k_edge<1><<<2048, 256, 0, stream>>>(x32, src_csr, dst_csr, eord, ewin, ew_csr, unoise,
                                        epW1, epb1, epW2, epb2, alphap, Pb32, Pc32,
                                        flagcnt, flaglist, out);
    k_fix<1><<<64, 256, 0, stream>>>(x32, src_csr, dst_csr, eord, ewin, ew_csr, unoise,
                                     epW1, epb1, epW2, epb2, alphap, Pb32, Pc32,
                                     flagcnt, flaglist, out);
    k_nodeup<1><<<2048, 256, 0, stream>>>(x32, ew_csr, src_csr, rowptr, ginW, ginB,
                                          xh32, bnacc);
    k_bnfin<<<1, 64, 0, stream>>>(1, bng, bnb, bnacc, bnsc);
    k_bnapply<1><<<2048, 256, 0, stream>>>(bnsc, xh32, x32, out);
    k_att1<<<1024, 256, 0, stream>>>(x32, c64, sc, bmax);
    k_att2<<<16, 64, 0, stream>>>(bmax, mxg, num, den);
    k_att3<<<1024, 256, 0, stream>>>(x32, sc, mxg, num, den);
    k_att4<<<16, 64, 0, stream>>>(num, den, c64);

    // ---------------- heads + centroid output ----------------
    k_head<<<2048, 256, 0, stream>>>(x32, c64, hW1, hb1, hW2, hb2, out);
}

// Round 14
// 963.936 us; speedup vs baseline: 1.2364x; 1.0006x over previous
//
#include <hip/hip_runtime.h>
#include <hip/hip_bf16.h>

// GraphCAD forward on MI355X. All float I/O is f32.
// R20->R21: k_edge is the remaining top kernel (177us x2, occ 39%). Its
// occupancy is LDS-capped: 34816B/block -> 4 blocks/CU (50% cap). The +4
// padding on both [64][68] arrays is bank-NEUTRAL (staging writes are 4-way
// at stride 68 AND 64: addr == const+eloc mod 32 either way since 64q==0;
// af reads are 4-address broadcasts; wf reads span 64 consecutive words =
// 2-way free; sred keeps its own stride-17 layout inside A, 1088<=4096).
// So strides go 68->64: LDS = 32768B exactly -> 5 blocks/CU = 62.5% occ cap.
// More resident waves -> more independent random-row streams -> less
// unhidden gather latency. Everything else identical to R20 (964us).

#define D 64
#define BSZ 16
#define NPG 4096
#define NN (BSZ * NPG)   // 65536 nodes
#define NE (NN * 16)     // 1048576 edges
#define NL 2
#define NTILE (NE / 64)  // 16384

#define FIXTH 2e-3f
#define FLAGCAP 65536

// output layout (elements, f32)
#define OUT_X  0u
#define OUT_EW 4194304u
#define OUT_C  5242880u
#define OUT_XL 5243904u
#define OUT_CL 9438208u
#define OUT_PA 9439232u

__device__ __forceinline__ void atomAdd64(double* p, double v) { unsafeAtomicAdd(p, v); }

// ================= CSR build (dst is a static input; rebuilt per call) ======
__global__ __launch_bounds__(256) void k_deg(const int* __restrict__ edst,
                                             int* __restrict__ cnt) {
    int stride = gridDim.x * 256;
    for (int e = blockIdx.x * 256 + threadIdx.x; e < NE; e += stride)
        atomicAdd(&cnt[edst[e]], 1);
}

__global__ __launch_bounds__(256) void k_scan1(const int* __restrict__ cnt,
                                               int* __restrict__ rowptr,
                                               int* __restrict__ bsum) {
    __shared__ int sd[256];
    const int b = blockIdx.x, t = threadIdx.x;
    const int v = cnt[b * 256 + t];
    sd[t] = v;
    __syncthreads();
    for (int off = 1; off < 256; off <<= 1) {
        int tmp = (t >= off) ? sd[t - off] : 0;
        __syncthreads();
        sd[t] += tmp;
        __syncthreads();
    }
    rowptr[b * 256 + t] = sd[t] - v;  // exclusive
    if (t == 255) bsum[b] = sd[255];
}

__global__ __launch_bounds__(256) void k_scan2(int* __restrict__ bsum) {
    __shared__ int sd[256];
    const int t = threadIdx.x;
    const int v = bsum[t];
    sd[t] = v;
    __syncthreads();
    for (int off = 1; off < 256; off <<= 1) {
        int tmp = (t >= off) ? sd[t - off] : 0;
        __syncthreads();
        sd[t] += tmp;
        __syncthreads();
    }
    bsum[t] = sd[t] - v;  // exclusive
}

__global__ __launch_bounds__(256) void k_scan3(const int* __restrict__ bsum,
                                               int* __restrict__ rowptr,
                                               int* __restrict__ cursor) {
    const int i = blockIdx.x * 256 + threadIdx.x;
    const int r = rowptr[i] + bsum[blockIdx.x];
    rowptr[i] = r;
    cursor[i] = r;
    if (i == 0) rowptr[NN] = NE;
}

// fill CSR: slot -> original edge (eord), src (src_csr), dst (dst_csr).
__global__ __launch_bounds__(256) void k_fill(const int* __restrict__ esrc,
                                              const int* __restrict__ edst,
                                              int* __restrict__ cursor,
                                              int* __restrict__ eord,
                                              int* __restrict__ src_csr,
                                              int* __restrict__ dst_csr) {
    int stride = gridDim.x * 256;
    for (int e = blockIdx.x * 256 + threadIdx.x; e < NE; e += stride) {
        const int d = edst[e];
        int pos = atomicAdd(&cursor[d], 1);
        eord[pos] = e;
        src_csr[pos] = esrc[e];
        dst_csr[pos] = d;
    }
}

// ---- initial centroid: per-graph mean of x (f32 in, f64 out), 8 blocks/graph
__global__ __launch_bounds__(256) void k_centroid0(const float* __restrict__ xin,
                                                   double* __restrict__ c64) {
    const int g = blockIdx.x >> 3, sub = blockIdx.x & 7, tid = threadIdx.x;
    const int r = tid >> 6, f = tid & 63;
    __shared__ double cr[4][D];
    double s = 0.0;
    for (int k = 0; k < NPG / 8 / 4; ++k) {
        size_t n = (size_t)g * NPG + (size_t)(sub * (NPG / 8) + 4 * k + r);
        s += (double)xin[n * D + f];
    }
    cr[r][f] = s;
    __syncthreads();
    if (tid < D)
        atomAdd64(&c64[g * D + tid],
                  (cr[0][tid] + cr[1][tid] + cr[2][tid] + cr[3][tid]) * (1.0 / NPG));
}

// ---- qb = c @ W1b, qc = c @ W1c (per graph, f64) ----
__global__ __launch_bounds__(256) void k_qbc(const double* __restrict__ c64,
                                             const float* __restrict__ epW1,
                                             double* __restrict__ qb, double* __restrict__ qc) {
    int gj = blockIdx.x * 256 + threadIdx.x;
    if (gj >= BSZ * D) return;
    int g = gj >> 6, j = gj & 63;
    double sb = 0.0, sc = 0.0;
#pragma unroll
    for (int i = 0; i < D; ++i) {
        double cv = c64[g * D + i];
        sb += cv * (double)epW1[(D + i) * D + j];
        sc += cv * (double)epW1[(2 * D + i) * D + j];
    }
    qb[gj] = sb;
    qc[gj] = sc;
}

// ---- P'_b = x@W1b - qb[g], P'_c = x@W1c - qc[g]; f32 compute/store ----
// f32 shift ~1e-6 on Pb/Pc; k_edge and k_fix both read these same values,
// so decisions stay consistent; |margin|<FIXTH edges go to k_fix regardless.
template <int LAYER>
__global__ __launch_bounds__(256) void k_P(const float* __restrict__ xin,
                                           const float* __restrict__ x32,
                                           const float* __restrict__ epW1,
                                           const double* __restrict__ qb,
                                           const double* __restrict__ qc,
                                           float* __restrict__ Pb, float* __restrict__ Pc,
                                           double* __restrict__ bnacc) {
    if (blockIdx.x == 0 && threadIdx.x < 128) bnacc[threadIdx.x] = 0.0;
    __shared__ float wb[D * D];
    __shared__ float wc[D * D];
    __shared__ float xrow[4][D];
    int tid = threadIdx.x, w = tid >> 6, j = tid & 63;
    for (int idx = tid; idx < D * D; idx += 256) {
        int i = idx >> 6, c = idx & 63;
        wb[idx] = epW1[(D + i) * D + c];
        wc[idx] = epW1[(2 * D + i) * D + c];
    }
    __syncthreads();
    for (int grp = blockIdx.x; grp < NN / 4; grp += gridDim.x) {
        size_t n = (size_t)grp * 4 + w;
        xrow[w][j] = (LAYER == 0) ? xin[n * D + j] : x32[n * D + j];
        __syncthreads();
        float pb = 0.0f, pc = 0.0f;
#pragma unroll
        for (int i = 0; i < D; ++i) {
            const float xv = xrow[w][i];
            pb += xv * wb[i * D + j];
            pc += xv * wc[i * D + j];
        }
        const int g = (int)(n >> 12);
        Pb[n * D + j] = pb - (float)qb[g * D + j];
        Pc[n * D + j] = pc - (float)qc[g * D + j];
        __syncthreads();
    }
}

// ---- edge scorer, CSR order: all-f32 tile GEMM + sample; near-threshold
// ---- edges (|score+g| < FIXTH) deferred to k_fix for exact f64 decision.
// LDS: A f32 [64][64] 16KB (reused as f32 sred, stride 17), W f32 [64][64]
// 16KB -> 32768B total = 5 blocks/CU (was 4 at [64][68]).
template <int LAYER>
__global__ __launch_bounds__(256, 4) void k_edge(const float* __restrict__ xsrc,
                                                 const int* __restrict__ src_csr,
                                                 const int* __restrict__ dst_csr,
                                                 const int* __restrict__ eord,
                                                 const float* __restrict__ ewin,
                                                 float* __restrict__ ew_csr,
                                                 const float* __restrict__ unoise,
                                                 const float* __restrict__ epW1,
                                                 const float* __restrict__ epb1,
                                                 const float* __restrict__ epW2,
                                                 const float* __restrict__ epb2,
                                                 const float* __restrict__ alphap,
                                                 const float* __restrict__ Pb32,
                                                 const float* __restrict__ Pc32,
                                                 int* __restrict__ flagcnt,
                                                 int* __restrict__ flaglist,
                                                 float* __restrict__ out) {
    const int t = threadIdx.x;
    const int tx = t & 15, ty = t >> 4;

    __shared__ __align__(16) float ldsA[64 * 64];  // |dx| [dim][slot]
    __shared__ __align__(16) float ldsW[64 * 64];  // W1a [k][j]

    for (int idx = t; idx < D * D; idx += 256) {
        ldsW[idx] = epW1[idx];  // [k][j] layout matches epW1 row-major
    }
    float b1f[4], w2f[4];
#pragma unroll
    for (int c = 0; c < 4; ++c) {
        b1f[c] = epb1[4 * tx + c];
        w2f[c] = epW2[4 * tx + c];
    }
    const float b2v = epb2[0];
    const float alpha = alphap[0];
    __syncthreads();

    const int eloc = t >> 2, q = t & 3;

    for (int tile = blockIdx.x; tile < NTILE; tile += gridDim.x) {
        const int base = tile * 64;

        // ---- stage |x_d - x_s| (f32, transposed). d-rows run-repeat (L1). --
        {
            const int pos = base + eloc;
            const int s = src_csr[pos], d = dst_csr[pos];
            const float* rs = xsrc + (size_t)s * D + q * 16;
            const float* rd = xsrc + (size_t)d * D + q * 16;
#pragma unroll
            for (int c = 0; c < 4; ++c) {
                const float4 fd = *(const float4*)(rd + 4 * c);
                const float4 fs = *(const float4*)(rs + 4 * c);
                const int dim = q * 16 + 4 * c;
                ldsA[(dim + 0) * 64 + eloc] = fabsf(fd.x - fs.x);
                ldsA[(dim + 1) * 64 + eloc] = fabsf(fd.y - fs.y);
                ldsA[(dim + 2) * 64 + eloc] = fabsf(fd.z - fs.z);
                ldsA[(dim + 3) * 64 + eloc] = fabsf(fd.w - fs.w);
            }
        }
        __syncthreads();

        // ---- 64x64x64 GEMM: f32 inputs, f32 accumulate, 4x4 per thread ----
        float acc[4][4];
#pragma unroll
        for (int r = 0; r < 4; ++r)
#pragma unroll
            for (int c = 0; c < 4; ++c) acc[r][c] = 0.0f;

#pragma unroll 4
        for (int k = 0; k < 64; ++k) {
            const float4 af = *(const float4*)&ldsA[k * 64 + 4 * ty];
            const float4 wf = *(const float4*)&ldsW[k * 64 + 4 * tx];
            const float av[4] = {af.x, af.y, af.z, af.w};
            const float wv[4] = {wf.x, wf.y, wf.z, wf.w};
#pragma unroll
            for (int r = 0; r < 4; ++r)
#pragma unroll
                for (int c = 0; c < 4; ++c) acc[r][c] += av[r] * wv[c];
        }
        __syncthreads();  // A dead -> reuse as f32 sred

        float* sred = ldsA;
        // ---- epilogue: + P' terms, +b1, relu, * w2, partial sums ----
#pragma unroll
        for (int r = 0; r < 4; ++r) {
            const int pos = base + 4 * ty + r;
            const int s = src_csr[pos], d = dst_csr[pos];
            const float4 pb = *(const float4*)(Pb32 + (size_t)d * D + 4 * tx);
            const float4 pc = *(const float4*)(Pc32 + (size_t)s * D + 4 * tx);
            float part = 0.0f;
            float h;
            h = acc[r][0] + pb.x + pc.x + b1f[0];
            if (h > 0.0f) part += h * w2f[0];
            h = acc[r][1] + pb.y + pc.y + b1f[1];
            if (h > 0.0f) part += h * w2f[1];
            h = acc[r][2] + pb.z + pc.z + b1f[2];
            if (h > 0.0f) part += h * w2f[2];
            h = acc[r][3] + pb.w + pc.w + b1f[3];
            if (h > 0.0f) part += h * w2f[3];
            sred[(4 * ty + r) * 17 + tx] = part;
        }
        __syncthreads();

        // ---- score reduce + RelaxedBernoulli sample (one lane per slot) ----
        if (t < 64) {
            float sc_ = b2v;
#pragma unroll
            for (int i = 0; i < 16; ++i) sc_ += sred[t * 17 + i];
            const int pos = base + t;
            const int e = eord[pos];
            const float u = unoise[(size_t)LAYER * NE + e];
            const float gn = logf(u) - log1pf(-u);
            const float mar = sc_ + gn;  // decision margin; samp == (mar > 0)
            bool deferred = false;
            if (fabsf(mar) < FIXTH) {
                int slot = atomicAdd(flagcnt, 1);
                if (slot < FLAGCAP) {
                    flaglist[slot] = pos;
                    deferred = true;  // k_fix decides + writes this edge
                }
            }
            if (!deferred) {
                const float pre = 1.0f / (1.0f + expf(-sc_));
                const bool samp = mar > 0.0f;
                const float ewo = (LAYER == 0) ? ewin[e] : ew_csr[pos];
                const float ewn = samp ? alpha * ewo + (1.0f - alpha) * pre : 0.0f;
                ew_csr[pos] = ewn;
                if (LAYER == NL - 1) {
                    out[OUT_EW + (size_t)e] = ewn;
                    out[OUT_PA + (size_t)e] = pre;
                }
            }
        }
        __syncthreads();
    }
}

// ---- exact f64 re-decision for near-threshold edges (one wave per edge) ----
template <int LAYER>
__global__ __launch_bounds__(256) void k_fix(const float* __restrict__ xsrc,
                                             const int* __restrict__ src_csr,
                                             const int* __restrict__ dst_csr,
                                             const int* __restrict__ eord,
                                             const float* __restrict__ ewin,
                                             float* __restrict__ ew_csr,
                                             const float* __restrict__ unoise,
                                             const float* __restrict__ epW1,
                                             const float* __restrict__ epb1,
                                             const float* __restrict__ epW2,
                                             const float* __restrict__ epb2,
                                             const float* __restrict__ alphap,
                                             const float* __restrict__ Pb32,
                                             const float* __restrict__ Pc32,
                                             const int* __restrict__ flagcnt,
                                             const int* __restrict__ flaglist,
                                             float* __restrict__ out) {
    const int n = min(flagcnt[0], FLAGCAP);
    __shared__ float dxs[4][D];
    const int w = threadIdx.x >> 6, lane = threadIdx.x & 63;
    const int nw = gridDim.x * 4;
    for (int i = blockIdx.x * 4 + w; i < n; i += nw) {
        const int pos = flaglist[i];
        const int s = src_csr[pos], d = dst_csr[pos];
        // |dx| from the same f32 inputs the main kernel staged
        dxs[w][lane] = fabsf(xsrc[(size_t)d * D + lane] - xsrc[(size_t)s * D + lane]);
        // wave-internal broadcast (same-wave DS in-order)
        double h = 0.0;
#pragma unroll
        for (int k = 0; k < D; ++k) h += (double)dxs[w][k] * (double)epW1[k * D + lane];
        h += (double)Pb32[(size_t)d * D + lane] + (double)Pc32[(size_t)s * D + lane] +
             (double)epb1[lane];
        double part = (h > 0.0) ? h * (double)epW2[lane] : 0.0;
#pragma unroll
        for (int off = 32; off; off >>= 1) part += __shfl_xor(part, off);
        if (lane == 0) {
            const double sc_ = part + (double)epb2[0];
            const int e = eord[pos];
            const double u = (double)unoise[(size_t)LAYER * NE + e];
            const double gn = log(u) - log1p(-u);
            const double pre = 1.0 / (1.0 + exp(-sc_));
            const bool samp = (sc_ + gn) > 0.0;
            const double ewo = (LAYER == 0) ? (double)ewin[e] : (double)ew_csr[pos];
            const double alpha = (double)alphap[0];
            const double ewn = samp ? alpha * ewo + (1.0 - alpha) * pre : 0.0;
            ew_csr[pos] = (float)ewn;
            if (LAYER == NL - 1) {
                out[OUT_EW + (size_t)e] = (float)ewn;
                out[OUT_PA + (size_t)e] = (float)pre;
            }
        }
    }
}

// ---- node update: CSR gather (row-parallel loads) + GIN mlp + BN partials --
// Lane = (slot e=0..3, quarter q=0..15). First 16 edges: 4 float4-load
// instructions x 4 rows each, issued back-to-back. f64 acc per (slot,4dims);
// tree-reduce slots (2x shfl_xor); + self; f64 matvec; xh stored f32
// (BN stats still from unrounded f64 h). bnacc block-reduced in LDS first.
template <int LAYER>
__global__ __launch_bounds__(256) void k_nodeup(const float* __restrict__ xsrc,
                                                const float* __restrict__ ew_csr,
                                                const int* __restrict__ src_csr,
                                                const int* __restrict__ rowptr,
                                                const float* __restrict__ ginW,
                                                const float* __restrict__ ginB,
                                                float* __restrict__ xh,
                                                double* __restrict__ bnacc) {
    __shared__ float wg[D * D];
    __shared__ double rowbuf[4][D];
    __shared__ double bn1[4][D];
    __shared__ double bn2[4][D];
    const int t = threadIdx.x, w = t >> 6, lane = t & 63;
    const int e = lane >> 4, q = lane & 15;  // slot, quarter (dims 4q..4q+3)
    for (int idx = t; idx < D * D; idx += 256) wg[idx] = ginW[LAYER * D * D + idx];
    const double bj = (double)ginB[LAYER * D + lane];
    __syncthreads();
    double s1 = 0.0, s2 = 0.0;
    const int nwaves = gridDim.x * 4;
    for (int n = blockIdx.x * 4 + w; n < NN; n += nwaves) {
        const int rs = rowptr[n], re = rowptr[n + 1];
        const int deg = re - rs;
        // ---- first 16 edges: 4 masked slots x 4 chunks, all loads up front
        const int i0 = rs + ((e < deg) ? e : 0);
        const int i1 = rs + ((4 + e < deg) ? 4 + e : 0);
        const int i2 = rs + ((8 + e < deg) ? 8 + e : 0);
        const int i3 = rs + ((12 + e < deg) ? 12 + e : 0);
        const float w0 = (e < deg) ? ew_csr[i0] : 0.f;
        const float w1 = (4 + e < deg) ? ew_csr[i1] : 0.f;
        const float w2 = (8 + e < deg) ? ew_csr[i2] : 0.f;
        const float w3 = (12 + e < deg) ? ew_csr[i3] : 0.f;
        const int s0 = src_csr[i0], s1_ = src_csr[i1];
        const int s2_ = src_csr[i2], s3_ = src_csr[i3];
        const float4 r0 = *(const float4*)(xsrc + (size_t)s0 * D + 4 * q);
        const float4 r1 = *(const float4*)(xsrc + (size_t)s1_ * D + 4 * q);
        const float4 r2 = *(const float4*)(xsrc + (size_t)s2_ * D + 4 * q);
        const float4 r3 = *(const float4*)(xsrc + (size_t)s3_ * D + 4 * q);
        const float4 rf = *(const float4*)(xsrc + (size_t)n * D + 4 * q);  // self
        double a0 = (double)w0 * (double)r0.x;
        double a1 = (double)w0 * (double)r0.y;
        double a2 = (double)w0 * (double)r0.z;
        double a3 = (double)w0 * (double)r0.w;
        a0 += (double)w1 * (double)r1.x;
        a1 += (double)w1 * (double)r1.y;
        a2 += (double)w1 * (double)r1.z;
        a3 += (double)w1 * (double)r1.w;
        a0 += (double)w2 * (double)r2.x;
        a1 += (double)w2 * (double)r2.y;
        a2 += (double)w2 * (double)r2.z;
        a3 += (double)w2 * (double)r2.w;
        a0 += (double)w3 * (double)r3.x;
        a1 += (double)w3 * (double)r3.y;
        a2 += (double)w3 * (double)r3.z;
        a3 += (double)w3 * (double)r3.w;
        // ---- tail: edges beyond 16, masked chunks of 4 (wave-uniform bound)
        for (int k = rs + 16; k < re; k += 4) {
            const int kk = k + e;
            const bool v = kk < re;
            const float wt = v ? ew_csr[kk] : 0.f;
            const int st = src_csr[v ? kk : rs];
            const float4 rt = *(const float4*)(xsrc + (size_t)st * D + 4 * q);
            a0 += (double)wt * (double)rt.x;
            a1 += (double)wt * (double)rt.y;
            a2 += (double)wt * (double)rt.z;
            a3 += (double)wt * (double)rt.w;
        }
        // ---- tree-reduce the 4 slots (lanes differing in bits 4,5) ----
        a0 += __shfl_xor(a0, 16);
        a1 += __shfl_xor(a1, 16);
        a2 += __shfl_xor(a2, 16);
        a3 += __shfl_xor(a3, 16);
        a0 += __shfl_xor(a0, 32);
        a1 += __shfl_xor(a1, 32);
        a2 += __shfl_xor(a2, 32);
        a3 += __shfl_xor(a3, 32);
        // ---- + self, publish to rowbuf (same-wave DS in-order) ----
        if (e == 0) {
            rowbuf[w][4 * q + 0] = a0 + (double)rf.x;
            rowbuf[w][4 * q + 1] = a1 + (double)rf.y;
            rowbuf[w][4 * q + 2] = a2 + (double)rf.z;
            rowbuf[w][4 * q + 3] = a3 + (double)rf.w;
        }
        // ---- GIN matvec (f64) ----
        double h = bj;
#pragma unroll
        for (int i = 0; i < D; ++i) h += rowbuf[w][i] * (double)wg[i * D + lane];
        h = h > 0.0 ? h : 0.0;
        xh[(size_t)n * D + lane] = (float)h;
        s1 += h;
        s2 += h * h;
    }
    // ---- block-level reduce, then 2 atomics per lane-column per block ----
    bn1[w][lane] = s1;
    bn2[w][lane] = s2;
    __syncthreads();
    if (w == 0) {
        atomAdd64(&bnacc[lane], bn1[0][lane] + bn1[1][lane] + bn1[2][lane] + bn1[3][lane]);
        atomAdd64(&bnacc[64 + lane], bn2[0][lane] + bn2[1][lane] + bn2[2][lane] + bn2[3][lane]);
    }
}

// ---- BN finalize ----
__global__ __launch_bounds__(64) void k_bnfin(int layer, const float* __restrict__ gamma,
                                              const float* __restrict__ beta,
                                              const double* __restrict__ bnacc,
                                              double* __restrict__ bnsc) {
    int j = threadIdx.x;
    double mu = bnacc[j] * (1.0 / NN);
    double var = bnacc[64 + j] * (1.0 / NN) - mu * mu;
    double sc = (double)gamma[layer * D + j] / sqrt(var + 1e-5);
    bnsc[j] = sc;
    bnsc[64 + j] = (double)beta[layer * D + j] - mu * sc;
}

// ---- BN apply -> x32 (f64 affine, single rounding; final out at layer 1) --
template <int LAYER>
__global__ __launch_bounds__(256) void k_bnapply(const double* __restrict__ bnsc,
                                                 const float* __restrict__ xh,
                                                 float* __restrict__ x32,
                                                 float* __restrict__ out) {
    size_t stride = (size_t)gridDim.x * 256;
    for (size_t i = (size_t)blockIdx.x * 256 + threadIdx.x; i < (size_t)NN * D; i += stride) {
        int j = (int)(i & 63);
        const float v = (float)(bnsc[j] * (double)xh[i] + bnsc[64 + j]);
        x32[i] = v;
        if (LAYER == NL - 1) out[OUT_X + i] = v;
    }
}

// ---- attention pooling, parallelized: 4 kernels (x in f32, math f64) ----
__global__ __launch_bounds__(256) void k_att1(const float* __restrict__ x32,
                                              const double* __restrict__ c64,
                                              double* __restrict__ sc,
                                              double* __restrict__ bmax) {
    const int blk = blockIdx.x, t = threadIdx.x, w = t >> 6, lane = t & 63;
    const int g = blk >> 6;
    __shared__ double wmax[4];
    const double cj = c64[g * D + lane];
    double locmax = -1e300;
    for (int m = 0; m < 16; ++m) {
        const int n = blk * 64 + w * 16 + m;
        double v = (double)x32[(size_t)n * D + lane] * cj;
#pragma unroll
        for (int off = 32; off; off >>= 1) v += __shfl_xor(v, off);
        if (lane == 0) sc[n] = v;
        locmax = fmax(locmax, v);
    }
    if (lane == 0) wmax[w] = locmax;
    __syncthreads();
    if (t == 0) bmax[blk] = fmax(fmax(wmax[0], wmax[1]), fmax(wmax[2], wmax[3]));
}

__global__ __launch_bounds__(64) void k_att2(const double* __restrict__ bmax,
                                             double* __restrict__ mxg,
                                             double* __restrict__ num,
                                             double* __restrict__ den) {
    const int g = blockIdx.x, t = threadIdx.x;
    double m = bmax[g * 64 + t];
#pragma unroll
    for (int off = 32; off; off >>= 1) m = fmax(m, __shfl_xor(m, off));
    if (t == 0) {
        mxg[g] = m;
        den[g] = 0.0;
    }
    num[g * D + t] = 0.0;
}

__global__ __launch_bounds__(256) void k_att3(const float* __restrict__ x32,
                                              const double* __restrict__ sc,
                                              const double* __restrict__ mxg,
                                              double* __restrict__ num,
                                              double* __restrict__ den) {
    const int blk = blockIdx.x, t = threadIdx.x, w = t >> 6, lane = t & 63;
    const int g = blk >> 6;
    __shared__ double cp[4][D];
    __shared__ double wes[4];
    const double mx = mxg[g];
    double accj = 0.0, esum = 0.0;
    for (int m = 0; m < 16; ++m) {
        const int n = blk * 64 + w * 16 + m;
        const double e = exp(sc[n] - mx);
        accj += e * (double)x32[(size_t)n * D + lane];
        esum += e;
    }
    cp[w][lane] = accj;
    if (lane == 0) wes[w] = esum;
    __syncthreads();
    if (t < D) {
        atomAdd64(&num[g * D + t], cp[0][t] + cp[1][t] + cp[2][t] + cp[3][t]);
        if (t == 0) atomAdd64(&den[g], wes[0] + wes[1] + wes[2] + wes[3]);
    }
}

__global__ __launch_bounds__(64) void k_att4(const double* __restrict__ num,
                                             const double* __restrict__ den,
                                             double* __restrict__ c64) {
    const int g = blockIdx.x, t = threadIdx.x;
    c64[g * D + t] = num[g * D + t] / den[g];
}

// ---- head: relu(x@W1+b1)@W2+b2 for all nodes + 16 centroid rows (f32) ----
__global__ __launch_bounds__(256) void k_head(const float* __restrict__ x32,
                                              const double* __restrict__ c64,
                                              const float* __restrict__ hW1,
                                              const float* __restrict__ hb1,
                                              const float* __restrict__ hW2,
                                              const float* __restrict__ hb2,
                                              float* __restrict__ out) {
    __shared__ float w1[D * D];
    __shared__ float w2[D * D];
    __shared__ float xr[4][D];
    __shared__ float hr[4][D];
    int tid = threadIdx.x, w = tid >> 6, j = tid & 63;
    for (int idx = tid; idx < D * D; idx += 256) {
        w1[idx] = hW1[idx];
        w2[idx] = hW2[idx];
    }
    const float b1j = hb1[j];
    const float b2j = hb2[j];
    __syncthreads();
    const int ROWS = NN + BSZ;
    for (int grp = blockIdx.x; grp * 4 < ROWS; grp += gridDim.x) {
        int r = grp * 4 + w;
        bool valid = r < ROWS;
        float xv = 0.f;
        if (valid)
            xv = (r < NN) ? x32[(size_t)r * D + j] : (float)c64[(size_t)(r - NN) * D + j];
        xr[w][j] = xv;
        __syncthreads();
        if (valid) {
            float h = b1j;
#pragma unroll
            for (int i = 0; i < D; ++i) h += xr[w][i] * w1[i * D + j];
            hr[w][j] = h > 0.f ? h : 0.f;
        }
        __syncthreads();
        if (valid) {
            float o = b2j;
#pragma unroll
            for (int i = 0; i < D; ++i) o += hr[w][i] * w2[i * D + j];
            if (r < NN) {
                out[OUT_XL + (size_t)r * D + j] = o;
            } else {
                size_t cr = (size_t)(r - NN) * D + j;
                out[OUT_CL + cr] = o;
                out[OUT_C + cr] = (float)c64[cr];
            }
        }
        __syncthreads();
    }
}

extern "C" void kernel_launch(void* const* d_in, const int* in_sizes, int n_in,
                              void* d_out, int out_size, void* d_ws, size_t ws_size,
                              hipStream_t stream) {
    const float* xin    = (const float*)d_in[0];
    const int*   ei     = (const int*)d_in[1];
    const float* ewin   = (const float*)d_in[2];
    const float* unoise = (const float*)d_in[5];
    const float* epW1   = (const float*)d_in[6];
    const float* epb1   = (const float*)d_in[7];
    const float* epW2   = (const float*)d_in[8];
    const float* epb2   = (const float*)d_in[9];
    const float* alphap = (const float*)d_in[10];
    const float* ginW   = (const float*)d_in[11];
    const float* ginB   = (const float*)d_in[12];
    const float* bng    = (const float*)d_in[13];
    const float* bnb    = (const float*)d_in[14];
    const float* hW1    = (const float*)d_in[15];
    const float* hb1    = (const float*)d_in[16];
    const float* hW2    = (const float*)d_in[17];
    const float* hb2    = (const float*)d_in[18];
    float* out = (float*)d_out;
    const int* esrc = ei;
    const int* edst = ei + NE;

    char* ws = (char*)d_ws;
    const size_t SZ4 = (size_t)NN * D * sizeof(float);  // 16MB
    // Pb (k_P->k_edge/k_fix) and xh (k_nodeup->k_bnapply): disjoint live ranges.
    float* Pb32 = (float*)(ws);
    float* xh32 = Pb32;  // alias
    float* Pc32 = (float*)(ws + SZ4);
    float* x32  = (float*)(ws + 2 * SZ4);
    float* ew_csr = (float*)(ws + 3 * SZ4);                       // NE*4 = 4MB
    double* sc  = (double*)(ws + 3 * SZ4 + (size_t)NE * 4);       // NN*8
    char*  p    = ws + 3 * SZ4 + (size_t)NE * 4 + (size_t)NN * 8;
    double* c64  = (double*)p;          p += BSZ * D * 8;
    double* qb   = (double*)p;          p += BSZ * D * 8;
    double* qc   = (double*)p;          p += BSZ * D * 8;
    double* bnacc = (double*)p;         p += 128 * 8;
    double* bnsc  = (double*)p;         p += 128 * 8;
    double* bmax  = (double*)p;         p += 1024 * 8;
    double* mxg   = (double*)p;         p += 16 * 8;
    double* num   = (double*)p;         p += BSZ * D * 8;
    double* den   = (double*)p;         p += 16 * 8;
    // CSR
    int* cnt     = (int*)p;             p += (size_t)NN * 4;
    int* rowptr  = (int*)p;             p += (size_t)(NN + 1) * 4 + 4;
    int* cursor  = (int*)p;             p += (size_t)NN * 4;
    int* bsum    = (int*)p;             p += 256 * 4;
    int* eord    = (int*)p;             p += (size_t)NE * 4;
    int* src_csr = (int*)p;             p += (size_t)NE * 4;
    int* dst_csr = (int*)p;             p += (size_t)NE * 4;
    // near-threshold fixup list
    int* flagcnt  = (int*)p;            p += 8;
    int* flaglist = (int*)p;            p += (size_t)FLAGCAP * 4;

    // ---- CSR build (dst static) ----
    hipMemsetAsync(cnt, 0, (size_t)NN * 4, stream);
    k_deg<<<1024, 256, 0, stream>>>(edst, cnt);
    k_scan1<<<256, 256, 0, stream>>>(cnt, rowptr, bsum);
    k_scan2<<<1, 256, 0, stream>>>(bsum);
    k_scan3<<<256, 256, 0, stream>>>(bsum, rowptr, cursor);
    k_fill<<<1024, 256, 0, stream>>>(esrc, edst, cursor, eord, src_csr, dst_csr);

    hipMemsetAsync(c64, 0, (size_t)BSZ * D * 8, stream);
    k_centroid0<<<BSZ * 8, 256, 0, stream>>>(xin, c64);

    // ---------------- layer 0 ----------------
    k_qbc<<<4, 256, 0, stream>>>(c64, epW1, qb, qc);
    k_P<0><<<2048, 256, 0, stream>>>(xin, x32, epW1, qb, qc, Pb32, Pc32, bnacc);
    hipMemsetAsync(flagcnt, 0, 4, stream);
    k_edge<0><<<2048, 256, 0, stream>>>(xin, src_csr, dst_csr, eord, ewin, ew_csr, unoise,
                                        epW1, epb1, epW2, epb2, alphap, Pb32, Pc32,
                                        flagcnt, flaglist, out);
    k_fix<0><<<64, 256, 0, stream>>>(xin, src_csr, dst_csr, eord, ewin, ew_csr, unoise,
                                     epW1, epb1, epW2, epb2, alphap, Pb32, Pc32,
                                     flagcnt, flaglist, out);
    k_nodeup<0><<<2048, 256, 0, stream>>>(xin, ew_csr, src_csr, rowptr, ginW, ginB,
                                          xh32, bnacc);
    k_bnfin<<<1, 64, 0, stream>>>(0, bng, bnb, bnacc, bnsc);
    k_bnapply<0><<<2048, 256, 0, stream>>>(bnsc, xh32, x32, out);
    k_att1<<<1024, 256, 0, stream>>>(x32, c64, sc, bmax);
    k_att2<<<16, 64, 0, stream>>>(bmax, mxg, num, den);
    k_att3<<<1024, 256, 0, stream>>>(x32, sc, mxg, num, den);
    k_att4<<<16, 64, 0, stream>>>(num, den, c64);

    // ---------------- layer 1 ----------------
    k_qbc<<<4, 256, 0, stream>>>(c64, epW1, qb, qc);
    k_P<1><<<2048, 256, 0, stream>>>(xin, x32, epW1, qb, qc, Pb32, Pc32, bnacc);
    hipMemsetAsync(flagcnt, 0, 4, stream);
    k_edge<1><<<2048, 256, 0, stream>>>(x32, src_csr, dst_csr, eord, ewin, ew_csr, unoise,
                                        epW1, epb1, epW2, epb2, alphap, Pb32, Pc32,
                                        flagcnt, flaglist, out);
    k_fix<1><<<64, 256, 0, stream>>>(x32, src_csr, dst_csr, eord, ewin, ew_csr, unoise,
                                     epW1, epb1, epW2, epb2, alphap, Pb32, Pc32,
                                     flagcnt, flaglist, out);
    k_nodeup<1><<<2048, 256, 0, stream>>>(x32, ew_csr, src_csr, rowptr, ginW, ginB,
                                          xh32, bnacc);
    k_bnfin<<<1, 64, 0, stream>>>(1, bng, bnb, bnacc, bnsc);
    k_bnapply<1><<<2048, 256, 0, stream>>>(bnsc, xh32, x32, out);
    k_att1<<<1024, 256, 0, stream>>>(x32, c64, sc, bmax);
    k_att2<<<16, 64, 0, stream>>>(bmax, mxg, num, den);
    k_att3<<<1024, 256, 0, stream>>>(x32, sc, mxg, num, den);
    k_att4<<<16, 64, 0, stream>>>(num, den, c64);

    // ---------------- heads + centroid output ----------------
    k_head<<<2048, 256, 0, stream>>>(x32, c64, hW1, hb1, hW2, hb2, out);
}